// Round 8
// baseline (748.182 us; speedup 1.0000x reference)
//
#include <hip/hip_runtime.h>
#include <hip/hip_bf16.h>
#include <stdint.h>

// ---------------------------------------------------------------------------
// CNNLSTM: conv1(6->64,k2) BN ReLU -> conv2(64->64,k2) BN ReLU ->
//          convT1(64->64,k2) BN ReLU -> convT2(64->64,k2) ReLU ->
//          LSTM(T=512, batch=1024, H=64) -> linear(64->1)
// Device I/O: FP32. Conv phases 2-4 on MFMA (bf16 in, fp32 accum); phase 1
// (K=6) VALU. LSTM: MFMA bf16, fp32 cell; raw s_barrier (lgkmcnt-only);
// 4-deep x register prefetch (load->use = 3 steps, covers ~900cyc HBM miss
// latency that stalled round-7 at 1-step distance); projection (OUT=1) fused
// into the step via shfl_xor reduce + psum LDS (kills proj_k + h stores).
// ws layout: 513 slots of 1024*64 bf16. conv writes x_t to slot t+1;
// LSTM reads slots 1..512.  ws bytes: 513*65536*2 = 67,239,936.
// ---------------------------------------------------------------------------

typedef __attribute__((ext_vector_type(8))) short bf16x8;
typedef __attribute__((ext_vector_type(4))) float f32x4;

__device__ __forceinline__ float bf2f(uint16_t u) {
  union { uint32_t i; float f; } v; v.i = ((uint32_t)u) << 16; return v.f;
}
__device__ __forceinline__ uint16_t f2bf(float f) {
  union { float f; uint32_t i; } v; v.f = f;
  return (uint16_t)((v.i + 0x7FFFu + ((v.i >> 16) & 1u)) >> 16);  // RNE
}
__device__ __forceinline__ float fexp(float x) { return __builtin_amdgcn_exp2f(x * 1.44269504088896340736f); }
__device__ __forceinline__ float frcp(float x) { return __builtin_amdgcn_rcpf(x); }
__device__ __forceinline__ float fsig(float x)  { return frcp(1.f + fexp(-x)); }
__device__ __forceinline__ float ftanh(float x) { return 1.f - 2.f * frcp(1.f + fexp(2.f * x)); }

#define MFMA16(a, b, c) __builtin_amdgcn_mfma_f32_16x16x32_bf16(a, b, c, 0, 0, 0)

// ============================ conv stack ===================================
#define YT   72
#define NROW 84
#define AST  136

template<int PHASE>
__device__ __forceinline__ void mfma_phase(
    const uint16_t* yin, uint16_t* yout, uint16_t* Xg, const uint16_t* wAs,
    const float* p_g, const float* p_be, const float* p_m, const float* p_v,
    const float* p_b, int lane, int wv, int l0)
{
  const int m0 = wv * 16;
  const int lm = lane & 15, lq = lane >> 4;
  float scr[4], tcr[4];
#pragma unroll
  for (int r = 0; r < 4; ++r) {
    int hr = m0 + lq * 4 + r;
    if constexpr (PHASE == 4) {
      scr[r] = 1.f; tcr[r] = p_b[hr];
    } else {
      float s = p_g[hr] * __builtin_amdgcn_rsqf(p_v[hr] + 1e-5f);
      scr[r] = s; tcr[r] = (p_b[hr] - p_m[hr]) * s + p_be[hr];
    }
  }
  bf16x8 af[4];
#pragma unroll
  for (int kc = 0; kc < 4; ++kc)
    af[kc] = *(const bf16x8*)&wAs[(m0 + lm) * AST + kc * 32 + lq * 8];
  const f32x4 Z = {0.f, 0.f, 0.f, 0.f};
#pragma unroll
  for (int nt = 0; nt < 5; ++nt) {
    f32x4 acc = Z;
#pragma unroll
    for (int kc = 0; kc < 4; ++kc) {
      int half = kc >> 1;
      int rT = nt * 16 + lm + 1 + (PHASE == 2 ? half : -half);
      bf16x8 bf_ = *(const bf16x8*)&yin[rT * YT + (kc & 1) * 32 + lq * 8];
      acc = MFMA16(af[kc], bf_, acc);
    }
    int il = nt * 16 + lm;
    int gl = l0 - 2 + il;
#pragma unroll
    for (int r = 0; r < 4; ++r) {
      int h = m0 + lq * 4 + r;
      float v = fmaxf(acc[r] * scr[r] + tcr[r], 0.f);
      if constexpr (PHASE == 2) {
        if (il < 66) yout[(il + 1) * YT + h] = (gl >= 0 && gl < 1022) ? f2bf(v) : (uint16_t)0;
      } else if constexpr (PHASE == 3) {
        if (il >= 1 && il < 66) yout[(il + 1) * YT + h] = (gl >= 0 && gl < 1023) ? f2bf(v) : (uint16_t)0;
      } else {
        if (il >= 2 && il < 66) Xg[(size_t)gl * 64 + h] = f2bf(v);
      }
    }
  }
}

__global__ __launch_bounds__(256, 3) void conv_stack_k(
    const float* __restrict__ inp,
    const float* __restrict__ w1p, const float* __restrict__ b1p,
    const float* __restrict__ g1p, const float* __restrict__ be1p,
    const float* __restrict__ m1p, const float* __restrict__ v1p,
    const float* __restrict__ w2p, const float* __restrict__ b2p,
    const float* __restrict__ g2p, const float* __restrict__ be2p,
    const float* __restrict__ m2p, const float* __restrict__ v2p,
    const float* __restrict__ t1p, const float* __restrict__ tb1p,
    const float* __restrict__ g3p, const float* __restrict__ be3p,
    const float* __restrict__ m3p, const float* __restrict__ v3p,
    const float* __restrict__ t2p, const float* __restrict__ tb2p,
    uint16_t* __restrict__ X)
{
  __shared__ __align__(16) uint16_t yTA[NROW * YT];
  __shared__ __align__(16) uint16_t yTB[NROW * YT];
  __shared__ __align__(16) uint16_t wAs[64 * AST];
  __shared__ float xs[6][YT];
  const int tid  = threadIdx.x;
  const int lane = tid & 63;
  const int wv   = tid >> 6;
  const int t    = blockIdx.y;
  const int l0   = blockIdx.x * 64;

  for (int i = tid; i < NROW * YT; i += 256) { yTA[i] = 0; yTB[i] = 0; }

  for (int i = tid; i < 6 * YT; i += 256) {
    int c = i % 6, il = i / 6;
    int gl = l0 - 2 + il;
    float v = 0.f;
    if (gl >= 0 && gl < 1024) v = inp[(size_t)t * 6144 + (size_t)gl * 6 + c];
    xs[c][il] = v;
  }

  for (int i = tid; i < 4096; i += 256) {
    int hh = i >> 6, cc = i & 63;
    float2 q = *(const float2*)(w2p + (size_t)i * 2);
    wAs[hh * AST + cc]      = f2bf(q.x);
    wAs[hh * AST + 64 + cc] = f2bf(q.y);
  }
  __syncthreads();

  // ---- phase 1 (VALU)
  {
    const int h = lane;
    float wr[12];
#pragma unroll
    for (int i = 0; i < 6; ++i) {
      float2 q = *(const float2*)(w1p + h * 12 + i * 2);
      wr[i * 2] = q.x; wr[i * 2 + 1] = q.y;
    }
    float sc = g1p[h] * __builtin_amdgcn_rsqf(v1p[h] + 1e-5f);
    float tc = (b1p[h] - m1p[h]) * sc + be1p[h];
#pragma unroll 1
    for (int base = wv * 4; base < 67; base += 16) {
      float a0 = 0, a1 = 0, a2 = 0, a3 = 0;
#pragma unroll
      for (int c = 0; c < 6; ++c) {
        float4 v = *(const float4*)&xs[c][base];
        float s4 = xs[c][base + 4];
        float k0 = wr[c * 2], k1 = wr[c * 2 + 1];
        a0 += v.x * k0 + v.y * k1;
        a1 += v.y * k0 + v.z * k1;
        a2 += v.z * k0 + v.w * k1;
        a3 += v.w * k0 + s4 * k1;
      }
      float r[4] = {a0, a1, a2, a3};
#pragma unroll
      for (int j = 0; j < 4; ++j) {
        int il = base + j;
        if (il < 67) {
          int gl = l0 - 2 + il;
          yTA[(il + 1) * YT + h] =
              (gl >= 0 && gl < 1023) ? f2bf(fmaxf(r[j] * sc + tc, 0.f)) : (uint16_t)0;
        }
      }
    }
  }
  __syncthreads();

  mfma_phase<2>(yTA, yTB, nullptr, wAs, g2p, be2p, m2p, v2p, b2p, lane, wv, l0);
  __syncthreads();

  for (int i = tid; i < 4096; i += 256) {
    int cc = i >> 6, hh = i & 63;
    float2 q = *(const float2*)(t1p + (size_t)i * 2);
    wAs[hh * AST + cc]      = f2bf(q.x);
    wAs[hh * AST + 64 + cc] = f2bf(q.y);
  }
  __syncthreads();

  mfma_phase<3>(yTB, yTA, nullptr, wAs, g3p, be3p, m3p, v3p, tb1p, lane, wv, l0);
  __syncthreads();

  for (int i = tid; i < 4096; i += 256) {
    int cc = i >> 6, hh = i & 63;
    float2 q = *(const float2*)(t2p + (size_t)i * 2);
    wAs[hh * AST + cc]      = f2bf(q.x);
    wAs[hh * AST + 64 + cc] = f2bf(q.y);
  }
  __syncthreads();

  mfma_phase<4>(yTA, nullptr, X + (size_t)(t + 1) * 65536, wAs,
                nullptr, nullptr, nullptr, nullptr, tb2p, lane, wv, l0);
}

// ============================== LSTM + fused projection =====================
// 64 blocks x 16 batch rows; 4 waves; wave w owns gate cols {16w,+64,+128,+192}.
// Per step t (in-order): prefetch x_{t+4} (3-step use distance) -> ds_read h
// -> flush out[t-1] (wave 0, psum parity buffer) -> h-MFMAs on precomputed
// x-part -> pointwise -> h to LDS + proj partial shfl-reduce to psum ->
// x-part MFMAs for t+1 -> lgkmcnt(0) + raw s_barrier (no vmcnt drain).
#define HSTR 72

#define LSTM_STEP(T_, AXC, AXN, XNB, XLD, BR, BW) do {                         \
    if ((T_) + 4 < 512) {                                                      \
      const uint16_t* xp_ = Xb + (size_t)((T_) + 5) * 65536                    \
                          + (size_t)(l0 + (lane & 15)) * 64 + kgrp;            \
      XLD[0] = *(const bf16x8*)xp_;                                            \
      XLD[1] = *(const bf16x8*)(xp_ + 32);                                     \
    }                                                                          \
    bf16x8 hf0_ = *(const bf16x8*)&hl[BR][(lane & 15) * HSTR + kgrp];          \
    bf16x8 hf1_ = *(const bf16x8*)&hl[BR][(lane & 15) * HSTR + 32 + kgrp];     \
    if (wv == 0 && (T_) > 0) {                                                 \
      int row_ = lane >> 2, j_ = lane & 3;                                     \
      float v_ = psum[((T_) - 1) & 1][j_][row_];                               \
      v_ += __shfl_xor(v_, 1); v_ += __shfl_xor(v_, 2);                        \
      if (j_ == 0)                                                             \
        outp[(size_t)((T_) - 1) * 1024 + l0 + row_] = v_ + obv;                \
    }                                                                          \
    f32x4 ai_ = AXC[0], af_ = AXC[1], ag_ = AXC[2], ao_ = AXC[3];              \
    ai_ = MFMA16(hf0_, bfr[0][2], ai_); af_ = MFMA16(hf0_, bfr[1][2], af_);    \
    ag_ = MFMA16(hf0_, bfr[2][2], ag_); ao_ = MFMA16(hf0_, bfr[3][2], ao_);    \
    ai_ = MFMA16(hf1_, bfr[0][3], ai_); af_ = MFMA16(hf1_, bfr[1][3], af_);    \
    ag_ = MFMA16(hf1_, bfr[2][3], ag_); ao_ = MFMA16(hf1_, bfr[3][3], ao_);    \
    _Pragma("unroll")                                                          \
    for (int r_ = 0; r_ < 4; ++r_) {                                           \
      float ii = fsig(ai_[r_] + bi0);                                          \
      float ff = fsig(af_[r_] + bi1);                                          \
      float gg = ftanh(ag_[r_] + bi2);                                         \
      float oo = fsig(ao_[r_] + bi3);                                          \
      creg[r_] = ff * creg[r_] + ii * gg;                                      \
      hprev[r_] = oo * ftanh(creg[r_]);                                        \
      hl[BW][(r0 + r_) * HSTR + hcol] = f2bf(hprev[r_]);                       \
      float pv_ = hprev[r_] * owv;                                             \
      pv_ += __shfl_xor(pv_, 1); pv_ += __shfl_xor(pv_, 2);                    \
      pv_ += __shfl_xor(pv_, 4); pv_ += __shfl_xor(pv_, 8);                    \
      if ((lane & 15) == 0) psum[(T_) & 1][wv][r0 + r_] = pv_;                 \
    }                                                                          \
    if ((T_) + 1 < 512) {                                                      \
      AXN[0] = MFMA16(XNB[1], bfr[0][1], MFMA16(XNB[0], bfr[0][0], Z4));       \
      AXN[1] = MFMA16(XNB[1], bfr[1][1], MFMA16(XNB[0], bfr[1][0], Z4));       \
      AXN[2] = MFMA16(XNB[1], bfr[2][1], MFMA16(XNB[0], bfr[2][0], Z4));       \
      AXN[3] = MFMA16(XNB[1], bfr[3][1], MFMA16(XNB[0], bfr[3][0], Z4));       \
    }                                                                          \
    asm volatile("s_waitcnt lgkmcnt(0)" ::: "memory");                         \
    __builtin_amdgcn_s_barrier();                                              \
    asm volatile("" ::: "memory");                                             \
  } while (0)

__global__ __launch_bounds__(256) void lstm_k(
    const float* __restrict__ h0p, const float* __restrict__ c0p,
    const float* __restrict__ wihp, const float* __restrict__ whhp,
    const float* __restrict__ bihp, const float* __restrict__ bhhp,
    const float* __restrict__ owp, const float* __restrict__ obp,
    uint16_t* __restrict__ Xb, float* __restrict__ outp)
{
  __shared__ __align__(16) uint16_t hl[2][16 * HSTR];
  __shared__ float psum[2][4][16];
  const int tid  = threadIdx.x;
  const int lane = tid & 63;
  const int wv   = tid >> 6;
  const int l0   = blockIdx.x << 4;
  const int hcol = (wv << 4) | (lane & 15);
  const int r0   = (lane >> 4) << 2;
  const int kgrp = (lane >> 4) << 3;
  const f32x4 Z4 = {0.f, 0.f, 0.f, 0.f};

  bf16x8 bfr[4][4];
#pragma unroll
  for (int nt = 0; nt < 4; ++nt) {
    int n = nt * 64 + hcol;
#pragma unroll
    for (int kc = 0; kc < 4; ++kc) {
      int k0 = kc * 32 + kgrp;
      const float* src = (k0 < 64) ? (wihp + (size_t)n * 64 + k0)
                                   : (whhp + (size_t)n * 64 + (k0 - 64));
      bf16x8 f;
#pragma unroll
      for (int j = 0; j < 8; ++j) f[j] = (short)f2bf(src[j]);
      bfr[nt][kc] = f;
    }
  }
  float bi0 = bihp[hcol]       + bhhp[hcol];
  float bi1 = bihp[64 + hcol]  + bhhp[64 + hcol];
  float bi2 = bihp[128 + hcol] + bhhp[128 + hcol];
  float bi3 = bihp[192 + hcol] + bhhp[192 + hcol];
  float owv = owp[hcol];
  float obv = obp[0];

  float creg[4], hprev[4] = {0.f, 0.f, 0.f, 0.f};
#pragma unroll
  for (int r = 0; r < 4; ++r)
    creg[r] = c0p[(size_t)(l0 + r0 + r) * 64 + hcol];

  {
    int row = tid >> 4, col = (tid & 15) << 2;
    const float* sp = h0p + (size_t)(l0 + row) * 64 + col;
    int b = row * HSTR + col;
    hl[0][b]     = f2bf(sp[0]); hl[0][b + 1] = f2bf(sp[1]);
    hl[0][b + 2] = f2bf(sp[2]); hl[0][b + 3] = f2bf(sp[3]);
  }

  // preload x_0..x_3 (slots 1..4); precompute x-part gates for t=0 from b0
  bf16x8 b0[2], b1[2], b2[2], b3[2];
  {
    const uint16_t* xp = Xb + 65536 + (size_t)(l0 + (lane & 15)) * 64 + kgrp;
    b0[0] = *(const bf16x8*)xp;            b0[1] = *(const bf16x8*)(xp + 32);
    xp += 65536;
    b1[0] = *(const bf16x8*)xp;            b1[1] = *(const bf16x8*)(xp + 32);
    xp += 65536;
    b2[0] = *(const bf16x8*)xp;            b2[1] = *(const bf16x8*)(xp + 32);
    xp += 65536;
    b3[0] = *(const bf16x8*)xp;            b3[1] = *(const bf16x8*)(xp + 32);
  }
  f32x4 axA[4], axB[4];
#pragma unroll
  for (int g = 0; g < 4; ++g)
    axA[g] = MFMA16(b0[1], bfr[g][1], MFMA16(b0[0], bfr[g][0], Z4));
  __syncthreads();

#pragma unroll 1
  for (int t = 0; t < 512; t += 4) {
    LSTM_STEP(t,     axA, axB, b1, b0, 0, 1);   // load x_{t+4} -> b0
    LSTM_STEP(t + 1, axB, axA, b2, b1, 1, 0);   // load x_{t+5} -> b1
    LSTM_STEP(t + 2, axA, axB, b3, b2, 0, 1);   // load x_{t+6} -> b2
    LSTM_STEP(t + 3, axB, axA, b0, b3, 1, 0);   // load x_{t+7} -> b3
  }

  // flush out[511] (psum parity 1; last step's barrier already done)
  if (wv == 0) {
    int row_ = lane >> 2, j_ = lane & 3;
    float v_ = psum[1][j_][row_];
    v_ += __shfl_xor(v_, 1); v_ += __shfl_xor(v_, 2);
    if (j_ == 0) outp[(size_t)511 * 1024 + l0 + row_] = v_ + obv;
  }

  // hT at out+524288, cT at out+589824 (fp32)
#pragma unroll
  for (int r = 0; r < 4; ++r) {
    int gr = l0 + r0 + r;
    outp[524288 + (size_t)gr * 64 + hcol] = hprev[r];
    outp[589824 + (size_t)gr * 64 + hcol] = creg[r];
  }
}

// ============================== launch =====================================
extern "C" void kernel_launch(void* const* d_in, const int* in_sizes, int n_in,
                              void* d_out, int out_size, void* d_ws, size_t ws_size,
                              hipStream_t stream)
{
  (void)in_sizes; (void)n_in; (void)out_size;
  if (ws_size < (size_t)513 * 65536 * 2) return;   // ws guard

  const float* inp = (const float*)d_in[0];
  const float* h0p = (const float*)d_in[1];
  const float* c0p = (const float*)d_in[2];
  const float* w1  = (const float*)d_in[3];
  const float* b1  = (const float*)d_in[4];
  const float* g1  = (const float*)d_in[5];
  const float* be1 = (const float*)d_in[6];
  const float* m1  = (const float*)d_in[7];
  const float* v1  = (const float*)d_in[8];
  const float* w2  = (const float*)d_in[9];
  const float* b2  = (const float*)d_in[10];
  const float* g2  = (const float*)d_in[11];
  const float* be2 = (const float*)d_in[12];
  const float* m2  = (const float*)d_in[13];
  const float* v2  = (const float*)d_in[14];
  const float* tw1 = (const float*)d_in[15];
  const float* tb1 = (const float*)d_in[16];
  const float* g3  = (const float*)d_in[17];
  const float* be3 = (const float*)d_in[18];
  const float* m3  = (const float*)d_in[19];
  const float* v3  = (const float*)d_in[20];
  const float* tw2 = (const float*)d_in[21];
  const float* tb2 = (const float*)d_in[22];
  const float* wih = (const float*)d_in[23];
  const float* whh = (const float*)d_in[24];
  const float* bih = (const float*)d_in[25];
  const float* bhh = (const float*)d_in[26];
  const float* ow  = (const float*)d_in[27];
  const float* ob  = (const float*)d_in[28];

  uint16_t* Xb   = (uint16_t*)d_ws;
  float*    outp = (float*)d_out;

  conv_stack_k<<<dim3(16, 512), 256, 0, stream>>>(
      inp, w1, b1, g1, be1, m1, v1, w2, b2, g2, be2, m2, v2,
      tw1, tb1, g3, be3, m3, v3, tw2, tb2, Xb);
  lstm_k<<<64, 256, 0, stream>>>(h0p, c0p, wih, whh, bih, bhh, ow, ob, Xb, outp);
}

// Round 9
// 478.492 us; speedup vs baseline: 1.5636x; 1.5636x over previous
//
#include <hip/hip_runtime.h>
#include <hip/hip_bf16.h>
#include <stdint.h>

// ---------------------------------------------------------------------------
// CNNLSTM: conv1(6->64,k2) BN ReLU -> conv2(64->64,k2) BN ReLU ->
//          convT1(64->64,k2) BN ReLU -> convT2(64->64,k2) ReLU ->
//          LSTM(T=512, batch=1024, H=64) -> linear(64->1)
// Device I/O: FP32. Conv phases 2-4 on MFMA; phase 1 (K=6) VALU.
// LSTM: MFMA bf16, fp32 cell; raw s_barrier (lgkmcnt-only); 2-deep x register
// prefetch; NO per-step global h-stores (round-7's 66MB store stream sat in
// the in-order vmcnt queue ahead of the x-loads -> per-step backpressure).
// Projection (OUT=1) done via MFMA against a B-fragment holding out_w in
// column 0: D col0 = h . ow, stored as one predicated float4 per step by
// wave 0 (round-8's shfl_xor version put 16 DS-ops on the critical path).
// ws layout: 513 slots of 1024*64 bf16. conv writes x_t to slot t+1;
// LSTM reads slots 1..512.  ws bytes: 513*65536*2 = 67,239,936.
// ---------------------------------------------------------------------------

typedef __attribute__((ext_vector_type(8))) short bf16x8;
typedef __attribute__((ext_vector_type(4))) float f32x4;

__device__ __forceinline__ float bf2f(uint16_t u) {
  union { uint32_t i; float f; } v; v.i = ((uint32_t)u) << 16; return v.f;
}
__device__ __forceinline__ uint16_t f2bf(float f) {
  union { float f; uint32_t i; } v; v.f = f;
  return (uint16_t)((v.i + 0x7FFFu + ((v.i >> 16) & 1u)) >> 16);  // RNE
}
__device__ __forceinline__ float fexp(float x) { return __builtin_amdgcn_exp2f(x * 1.44269504088896340736f); }
__device__ __forceinline__ float frcp(float x) { return __builtin_amdgcn_rcpf(x); }
__device__ __forceinline__ float fsig(float x)  { return frcp(1.f + fexp(-x)); }
__device__ __forceinline__ float ftanh(float x) { return 1.f - 2.f * frcp(1.f + fexp(2.f * x)); }

#define MFMA16(a, b, c) __builtin_amdgcn_mfma_f32_16x16x32_bf16(a, b, c, 0, 0, 0)

// ============================ conv stack ===================================
#define YT   72
#define NROW 84
#define AST  136

template<int PHASE>
__device__ __forceinline__ void mfma_phase(
    const uint16_t* yin, uint16_t* yout, uint16_t* Xg, const uint16_t* wAs,
    const float* p_g, const float* p_be, const float* p_m, const float* p_v,
    const float* p_b, int lane, int wv, int l0)
{
  const int m0 = wv * 16;
  const int lm = lane & 15, lq = lane >> 4;
  float scr[4], tcr[4];
#pragma unroll
  for (int r = 0; r < 4; ++r) {
    int hr = m0 + lq * 4 + r;
    if constexpr (PHASE == 4) {
      scr[r] = 1.f; tcr[r] = p_b[hr];
    } else {
      float s = p_g[hr] * __builtin_amdgcn_rsqf(p_v[hr] + 1e-5f);
      scr[r] = s; tcr[r] = (p_b[hr] - p_m[hr]) * s + p_be[hr];
    }
  }
  bf16x8 af[4];
#pragma unroll
  for (int kc = 0; kc < 4; ++kc)
    af[kc] = *(const bf16x8*)&wAs[(m0 + lm) * AST + kc * 32 + lq * 8];
  const f32x4 Z = {0.f, 0.f, 0.f, 0.f};
#pragma unroll
  for (int nt = 0; nt < 5; ++nt) {
    f32x4 acc = Z;
#pragma unroll
    for (int kc = 0; kc < 4; ++kc) {
      int half = kc >> 1;
      int rT = nt * 16 + lm + 1 + (PHASE == 2 ? half : -half);
      bf16x8 bf_ = *(const bf16x8*)&yin[rT * YT + (kc & 1) * 32 + lq * 8];
      acc = MFMA16(af[kc], bf_, acc);
    }
    int il = nt * 16 + lm;
    int gl = l0 - 2 + il;
#pragma unroll
    for (int r = 0; r < 4; ++r) {
      int h = m0 + lq * 4 + r;
      float v = fmaxf(acc[r] * scr[r] + tcr[r], 0.f);
      if constexpr (PHASE == 2) {
        if (il < 66) yout[(il + 1) * YT + h] = (gl >= 0 && gl < 1022) ? f2bf(v) : (uint16_t)0;
      } else if constexpr (PHASE == 3) {
        if (il >= 1 && il < 66) yout[(il + 1) * YT + h] = (gl >= 0 && gl < 1023) ? f2bf(v) : (uint16_t)0;
      } else {
        if (il >= 2 && il < 66) Xg[(size_t)gl * 64 + h] = f2bf(v);
      }
    }
  }
}

__global__ __launch_bounds__(256, 3) void conv_stack_k(
    const float* __restrict__ inp,
    const float* __restrict__ w1p, const float* __restrict__ b1p,
    const float* __restrict__ g1p, const float* __restrict__ be1p,
    const float* __restrict__ m1p, const float* __restrict__ v1p,
    const float* __restrict__ w2p, const float* __restrict__ b2p,
    const float* __restrict__ g2p, const float* __restrict__ be2p,
    const float* __restrict__ m2p, const float* __restrict__ v2p,
    const float* __restrict__ t1p, const float* __restrict__ tb1p,
    const float* __restrict__ g3p, const float* __restrict__ be3p,
    const float* __restrict__ m3p, const float* __restrict__ v3p,
    const float* __restrict__ t2p, const float* __restrict__ tb2p,
    uint16_t* __restrict__ X)
{
  __shared__ __align__(16) uint16_t yTA[NROW * YT];
  __shared__ __align__(16) uint16_t yTB[NROW * YT];
  __shared__ __align__(16) uint16_t wAs[64 * AST];
  __shared__ float xs[6][YT];
  const int tid  = threadIdx.x;
  const int lane = tid & 63;
  const int wv   = tid >> 6;
  const int t    = blockIdx.y;
  const int l0   = blockIdx.x * 64;

  for (int i = tid; i < NROW * YT; i += 256) { yTA[i] = 0; yTB[i] = 0; }

  for (int i = tid; i < 6 * YT; i += 256) {
    int c = i % 6, il = i / 6;
    int gl = l0 - 2 + il;
    float v = 0.f;
    if (gl >= 0 && gl < 1024) v = inp[(size_t)t * 6144 + (size_t)gl * 6 + c];
    xs[c][il] = v;
  }

  for (int i = tid; i < 4096; i += 256) {
    int hh = i >> 6, cc = i & 63;
    float2 q = *(const float2*)(w2p + (size_t)i * 2);
    wAs[hh * AST + cc]      = f2bf(q.x);
    wAs[hh * AST + 64 + cc] = f2bf(q.y);
  }
  __syncthreads();

  // ---- phase 1 (VALU)
  {
    const int h = lane;
    float wr[12];
#pragma unroll
    for (int i = 0; i < 6; ++i) {
      float2 q = *(const float2*)(w1p + h * 12 + i * 2);
      wr[i * 2] = q.x; wr[i * 2 + 1] = q.y;
    }
    float sc = g1p[h] * __builtin_amdgcn_rsqf(v1p[h] + 1e-5f);
    float tc = (b1p[h] - m1p[h]) * sc + be1p[h];
#pragma unroll 1
    for (int base = wv * 4; base < 67; base += 16) {
      float a0 = 0, a1 = 0, a2 = 0, a3 = 0;
#pragma unroll
      for (int c = 0; c < 6; ++c) {
        float4 v = *(const float4*)&xs[c][base];
        float s4 = xs[c][base + 4];
        float k0 = wr[c * 2], k1 = wr[c * 2 + 1];
        a0 += v.x * k0 + v.y * k1;
        a1 += v.y * k0 + v.z * k1;
        a2 += v.z * k0 + v.w * k1;
        a3 += v.w * k0 + s4 * k1;
      }
      float r[4] = {a0, a1, a2, a3};
#pragma unroll
      for (int j = 0; j < 4; ++j) {
        int il = base + j;
        if (il < 67) {
          int gl = l0 - 2 + il;
          yTA[(il + 1) * YT + h] =
              (gl >= 0 && gl < 1023) ? f2bf(fmaxf(r[j] * sc + tc, 0.f)) : (uint16_t)0;
        }
      }
    }
  }
  __syncthreads();

  mfma_phase<2>(yTA, yTB, nullptr, wAs, g2p, be2p, m2p, v2p, b2p, lane, wv, l0);
  __syncthreads();

  for (int i = tid; i < 4096; i += 256) {
    int cc = i >> 6, hh = i & 63;
    float2 q = *(const float2*)(t1p + (size_t)i * 2);
    wAs[hh * AST + cc]      = f2bf(q.x);
    wAs[hh * AST + 64 + cc] = f2bf(q.y);
  }
  __syncthreads();

  mfma_phase<3>(yTB, yTA, nullptr, wAs, g3p, be3p, m3p, v3p, tb1p, lane, wv, l0);
  __syncthreads();

  for (int i = tid; i < 4096; i += 256) {
    int cc = i >> 6, hh = i & 63;
    float2 q = *(const float2*)(t2p + (size_t)i * 2);
    wAs[hh * AST + cc]      = f2bf(q.x);
    wAs[hh * AST + 64 + cc] = f2bf(q.y);
  }
  __syncthreads();

  mfma_phase<4>(yTA, nullptr, X + (size_t)(t + 1) * 65536, wAs,
                nullptr, nullptr, nullptr, nullptr, tb2p, lane, wv, l0);
}

// ============================== LSTM + MFMA projection ======================
// 64 blocks x 16 batch rows; 4 waves; wave w owns gate cols {16w,+64,+128,+192}.
// Per step T: prefetch x_{T+2} -> ds_read h_{T-1} fragments -> wave0: proj
// MFMA (out[T-1] = h_{T-1}.ow, col-0 trick) + one predicated float4 store ->
// h-MFMAs on precomputed x-part -> pointwise -> h to LDS (only) ->
// x-part MFMAs for T+1 -> lgkmcnt(0) + raw s_barrier. No global h traffic.
#define HSTR 72

#define LSTM_STEP(T_, AXC, AXN, XNB, XLD, BR, BW) do {                         \
    if ((T_) + 2 < 512) {                                                      \
      const uint16_t* xp_ = Xb + (size_t)((T_) + 3) * 65536                    \
                          + (size_t)(l0 + (lane & 15)) * 64 + kgrp;            \
      XLD[0] = *(const bf16x8*)xp_;                                            \
      XLD[1] = *(const bf16x8*)(xp_ + 32);                                     \
    }                                                                          \
    bf16x8 hf0_ = *(const bf16x8*)&hl[BR][(lane & 15) * HSTR + kgrp];          \
    bf16x8 hf1_ = *(const bf16x8*)&hl[BR][(lane & 15) * HSTR + 32 + kgrp];     \
    if (wv == 0 && (T_) > 0) {                                                 \
      f32x4 pr_ = MFMA16(hf1_, owf1, MFMA16(hf0_, owf0, Z4));                  \
      if ((lane & 15) == 0) {                                                  \
        float4 st_;                                                            \
        st_.x = pr_[0] + obv; st_.y = pr_[1] + obv;                            \
        st_.z = pr_[2] + obv; st_.w = pr_[3] + obv;                            \
        *(float4*)&outp[(size_t)((T_) - 1) * 1024 + l0 + ((lane >> 4) << 2)] = st_; \
      }                                                                        \
    }                                                                          \
    f32x4 ai_ = AXC[0], af_ = AXC[1], ag_ = AXC[2], ao_ = AXC[3];              \
    ai_ = MFMA16(hf0_, bfr[0][2], ai_); af_ = MFMA16(hf0_, bfr[1][2], af_);    \
    ag_ = MFMA16(hf0_, bfr[2][2], ag_); ao_ = MFMA16(hf0_, bfr[3][2], ao_);    \
    ai_ = MFMA16(hf1_, bfr[0][3], ai_); af_ = MFMA16(hf1_, bfr[1][3], af_);    \
    ag_ = MFMA16(hf1_, bfr[2][3], ag_); ao_ = MFMA16(hf1_, bfr[3][3], ao_);    \
    _Pragma("unroll")                                                          \
    for (int r_ = 0; r_ < 4; ++r_) {                                           \
      float ii = fsig(ai_[r_] + bi0);                                          \
      float ff = fsig(af_[r_] + bi1);                                          \
      float gg = ftanh(ag_[r_] + bi2);                                         \
      float oo = fsig(ao_[r_] + bi3);                                          \
      creg[r_] = ff * creg[r_] + ii * gg;                                      \
      hprev[r_] = oo * ftanh(creg[r_]);                                        \
      hl[BW][(r0 + r_) * HSTR + hcol] = f2bf(hprev[r_]);                       \
    }                                                                          \
    if ((T_) + 1 < 512) {                                                      \
      AXN[0] = MFMA16(XNB[1], bfr[0][1], MFMA16(XNB[0], bfr[0][0], Z4));       \
      AXN[1] = MFMA16(XNB[1], bfr[1][1], MFMA16(XNB[0], bfr[1][0], Z4));       \
      AXN[2] = MFMA16(XNB[1], bfr[2][1], MFMA16(XNB[0], bfr[2][0], Z4));       \
      AXN[3] = MFMA16(XNB[1], bfr[3][1], MFMA16(XNB[0], bfr[3][0], Z4));       \
    }                                                                          \
    asm volatile("s_waitcnt lgkmcnt(0)" ::: "memory");                         \
    __builtin_amdgcn_s_barrier();                                              \
    asm volatile("" ::: "memory");                                             \
  } while (0)

__global__ __launch_bounds__(256) void lstm_k(
    const float* __restrict__ h0p, const float* __restrict__ c0p,
    const float* __restrict__ wihp, const float* __restrict__ whhp,
    const float* __restrict__ bihp, const float* __restrict__ bhhp,
    const float* __restrict__ owp, const float* __restrict__ obp,
    uint16_t* __restrict__ Xb, float* __restrict__ outp)
{
  __shared__ __align__(16) uint16_t hl[2][16 * HSTR];
  const int tid  = threadIdx.x;
  const int lane = tid & 63;
  const int wv   = tid >> 6;
  const int l0   = blockIdx.x << 4;
  const int hcol = (wv << 4) | (lane & 15);
  const int r0   = (lane >> 4) << 2;
  const int kgrp = (lane >> 4) << 3;
  const f32x4 Z4 = {0.f, 0.f, 0.f, 0.f};

  bf16x8 bfr[4][4];
#pragma unroll
  for (int nt = 0; nt < 4; ++nt) {
    int n = nt * 64 + hcol;
#pragma unroll
    for (int kc = 0; kc < 4; ++kc) {
      int k0 = kc * 32 + kgrp;
      const float* src = (k0 < 64) ? (wihp + (size_t)n * 64 + k0)
                                   : (whhp + (size_t)n * 64 + (k0 - 64));
      bf16x8 f;
#pragma unroll
      for (int j = 0; j < 8; ++j) f[j] = (short)f2bf(src[j]);
      bfr[nt][kc] = f;
    }
  }
  float bi0 = bihp[hcol]       + bhhp[hcol];
  float bi1 = bihp[64 + hcol]  + bhhp[64 + hcol];
  float bi2 = bihp[128 + hcol] + bhhp[128 + hcol];
  float bi3 = bihp[192 + hcol] + bhhp[192 + hcol];
  float obv = obp[0];

  // projection B-fragments: col 0 holds ow[k], other cols zero
  bf16x8 owf0 = {0, 0, 0, 0, 0, 0, 0, 0}, owf1 = {0, 0, 0, 0, 0, 0, 0, 0};
  if ((lane & 15) == 0) {
#pragma unroll
    for (int j = 0; j < 8; ++j) {
      owf0[j] = (short)f2bf(owp[kgrp + j]);
      owf1[j] = (short)f2bf(owp[32 + kgrp + j]);
    }
  }

  float creg[4], hprev[4] = {0.f, 0.f, 0.f, 0.f};
#pragma unroll
  for (int r = 0; r < 4; ++r)
    creg[r] = c0p[(size_t)(l0 + r0 + r) * 64 + hcol];

  {
    int row = tid >> 4, col = (tid & 15) << 2;
    const float* sp = h0p + (size_t)(l0 + row) * 64 + col;
    int b = row * HSTR + col;
    hl[0][b]     = f2bf(sp[0]); hl[0][b + 1] = f2bf(sp[1]);
    hl[0][b + 2] = f2bf(sp[2]); hl[0][b + 3] = f2bf(sp[3]);
  }

  // preload x_0 (slot 1), x_1 (slot 2); precompute x-part gates for t=0
  bf16x8 xA[2], xB[2];
  {
    const uint16_t* xp = Xb + 65536 + (size_t)(l0 + (lane & 15)) * 64 + kgrp;
    xA[0] = *(const bf16x8*)xp;
    xA[1] = *(const bf16x8*)(xp + 32);
    const uint16_t* xq = xp + 65536;
    xB[0] = *(const bf16x8*)xq;
    xB[1] = *(const bf16x8*)(xq + 32);
  }
  f32x4 axA[4], axB[4];
#pragma unroll
  for (int g = 0; g < 4; ++g)
    axA[g] = MFMA16(xA[1], bfr[g][1], MFMA16(xA[0], bfr[g][0], Z4));
  __syncthreads();

#pragma unroll 1
  for (int t2 = 0; t2 < 512; t2 += 2) {
    LSTM_STEP(t2,     axA, axB, xB, xA, 0, 1);
    LSTM_STEP(t2 + 1, axB, axA, xA, xB, 1, 0);
  }

  // out[511]: h_511 sits in hl[0] (step 511 wrote BW=0; its barrier passed)
  if (wv == 0) {
    bf16x8 hf0 = *(const bf16x8*)&hl[0][(lane & 15) * HSTR + kgrp];
    bf16x8 hf1 = *(const bf16x8*)&hl[0][(lane & 15) * HSTR + 32 + kgrp];
    f32x4 pr = MFMA16(hf1, owf1, MFMA16(hf0, owf0, Z4));
    if ((lane & 15) == 0) {
      float4 st;
      st.x = pr[0] + obv; st.y = pr[1] + obv; st.z = pr[2] + obv; st.w = pr[3] + obv;
      *(float4*)&outp[(size_t)511 * 1024 + l0 + ((lane >> 4) << 2)] = st;
    }
  }

  // hT at out+524288, cT at out+589824 (fp32)
#pragma unroll
  for (int r = 0; r < 4; ++r) {
    int gr = l0 + r0 + r;
    outp[524288 + (size_t)gr * 64 + hcol] = hprev[r];
    outp[589824 + (size_t)gr * 64 + hcol] = creg[r];
  }
}

// ============================== launch =====================================
extern "C" void kernel_launch(void* const* d_in, const int* in_sizes, int n_in,
                              void* d_out, int out_size, void* d_ws, size_t ws_size,
                              hipStream_t stream)
{
  (void)in_sizes; (void)n_in; (void)out_size;
  if (ws_size < (size_t)513 * 65536 * 2) return;   // ws guard

  const float* inp = (const float*)d_in[0];
  const float* h0p = (const float*)d_in[1];
  const float* c0p = (const float*)d_in[2];
  const float* w1  = (const float*)d_in[3];
  const float* b1  = (const float*)d_in[4];
  const float* g1  = (const float*)d_in[5];
  const float* be1 = (const float*)d_in[6];
  const float* m1  = (const float*)d_in[7];
  const float* v1  = (const float*)d_in[8];
  const float* w2  = (const float*)d_in[9];
  const float* b2  = (const float*)d_in[10];
  const float* g2  = (const float*)d_in[11];
  const float* be2 = (const float*)d_in[12];
  const float* m2  = (const float*)d_in[13];
  const float* v2  = (const float*)d_in[14];
  const float* tw1 = (const float*)d_in[15];
  const float* tb1 = (const float*)d_in[16];
  const float* g3  = (const float*)d_in[17];
  const float* be3 = (const float*)d_in[18];
  const float* m3  = (const float*)d_in[19];
  const float* v3  = (const float*)d_in[20];
  const float* tw2 = (const float*)d_in[21];
  const float* tb2 = (const float*)d_in[22];
  const float* wih = (const float*)d_in[23];
  const float* whh = (const float*)d_in[24];
  const float* bih = (const float*)d_in[25];
  const float* bhh = (const float*)d_in[26];
  const float* ow  = (const float*)d_in[27];
  const float* ob  = (const float*)d_in[28];

  uint16_t* Xb   = (uint16_t*)d_ws;
  float*    outp = (float*)d_out;

  conv_stack_k<<<dim3(16, 512), 256, 0, stream>>>(
      inp, w1, b1, g1, be1, m1, v1, w2, b2, g2, be2, m2, v2,
      tw1, tb1, g3, be3, m3, v3, tw2, tb2, Xb);
  lstm_k<<<64, 256, 0, stream>>>(h0p, c0p, wih, whh, bih, bhh, ow, ob, Xb, outp);
}

// Round 10
// 307.549 us; speedup vs baseline: 2.4327x; 1.5558x over previous
//
#include <hip/hip_runtime.h>
#include <hip/hip_bf16.h>
#include <stdint.h>

// ---------------------------------------------------------------------------
// CNNLSTM: conv stack (MFMA phases 2-4) -> LSTM(T=512,batch=1024,H=64) -> proj
// LSTM v10: 256 blocks x 4 batch rows (all CUs), 4 waves split 64 gate-cols
// each; ONE cell per lane. A-fragment content tricks (D row i = A row i):
//  h-part:  A row i = h[i>>2]            -> acc[r] = row lq for all r
//  x-part:  A row i = x[t0+(i&3)][i>>2]  -> acc[g][r] = x-gate of step t0+r
// so x-gates for 4 steps come from one 8-MFMA batch with no cross-lane moves.
// Bias pre-seeded in MFMA C-in. Proj via col-0 MFMA on wave 0 (round-9).
// Raw s_barrier (lgkmcnt-only) per step; h in 2x(4x72) LDS double buffer.
// ws layout: 513 slots of 1024*64 bf16; conv writes x_t to slot t+1.
// ---------------------------------------------------------------------------

typedef __attribute__((ext_vector_type(8))) short bf16x8;
typedef __attribute__((ext_vector_type(4))) float f32x4;

__device__ __forceinline__ float bf2f(uint16_t u) {
  union { uint32_t i; float f; } v; v.i = ((uint32_t)u) << 16; return v.f;
}
__device__ __forceinline__ uint16_t f2bf(float f) {
  union { float f; uint32_t i; } v; v.f = f;
  return (uint16_t)((v.i + 0x7FFFu + ((v.i >> 16) & 1u)) >> 16);  // RNE
}
__device__ __forceinline__ float fexp(float x) { return __builtin_amdgcn_exp2f(x * 1.44269504088896340736f); }
__device__ __forceinline__ float frcp(float x) { return __builtin_amdgcn_rcpf(x); }
__device__ __forceinline__ float fsig(float x)  { return frcp(1.f + fexp(-x)); }
__device__ __forceinline__ float ftanh(float x) { return 1.f - 2.f * frcp(1.f + fexp(2.f * x)); }

#define MFMA16(a, b, c) __builtin_amdgcn_mfma_f32_16x16x32_bf16(a, b, c, 0, 0, 0)

// ============================ conv stack (unchanged) ========================
#define YT   72
#define NROW 84
#define AST  136

template<int PHASE>
__device__ __forceinline__ void mfma_phase(
    const uint16_t* yin, uint16_t* yout, uint16_t* Xg, const uint16_t* wAs,
    const float* p_g, const float* p_be, const float* p_m, const float* p_v,
    const float* p_b, int lane, int wv, int l0)
{
  const int m0 = wv * 16;
  const int lm = lane & 15, lq = lane >> 4;
  float scr[4], tcr[4];
#pragma unroll
  for (int r = 0; r < 4; ++r) {
    int hr = m0 + lq * 4 + r;
    if constexpr (PHASE == 4) {
      scr[r] = 1.f; tcr[r] = p_b[hr];
    } else {
      float s = p_g[hr] * __builtin_amdgcn_rsqf(p_v[hr] + 1e-5f);
      scr[r] = s; tcr[r] = (p_b[hr] - p_m[hr]) * s + p_be[hr];
    }
  }
  bf16x8 af[4];
#pragma unroll
  for (int kc = 0; kc < 4; ++kc)
    af[kc] = *(const bf16x8*)&wAs[(m0 + lm) * AST + kc * 32 + lq * 8];
  const f32x4 Z = {0.f, 0.f, 0.f, 0.f};
#pragma unroll
  for (int nt = 0; nt < 5; ++nt) {
    f32x4 acc = Z;
#pragma unroll
    for (int kc = 0; kc < 4; ++kc) {
      int half = kc >> 1;
      int rT = nt * 16 + lm + 1 + (PHASE == 2 ? half : -half);
      bf16x8 bf_ = *(const bf16x8*)&yin[rT * YT + (kc & 1) * 32 + lq * 8];
      acc = MFMA16(af[kc], bf_, acc);
    }
    int il = nt * 16 + lm;
    int gl = l0 - 2 + il;
#pragma unroll
    for (int r = 0; r < 4; ++r) {
      int h = m0 + lq * 4 + r;
      float v = fmaxf(acc[r] * scr[r] + tcr[r], 0.f);
      if constexpr (PHASE == 2) {
        if (il < 66) yout[(il + 1) * YT + h] = (gl >= 0 && gl < 1022) ? f2bf(v) : (uint16_t)0;
      } else if constexpr (PHASE == 3) {
        if (il >= 1 && il < 66) yout[(il + 1) * YT + h] = (gl >= 0 && gl < 1023) ? f2bf(v) : (uint16_t)0;
      } else {
        if (il >= 2 && il < 66) Xg[(size_t)gl * 64 + h] = f2bf(v);
      }
    }
  }
}

__global__ __launch_bounds__(256, 3) void conv_stack_k(
    const float* __restrict__ inp,
    const float* __restrict__ w1p, const float* __restrict__ b1p,
    const float* __restrict__ g1p, const float* __restrict__ be1p,
    const float* __restrict__ m1p, const float* __restrict__ v1p,
    const float* __restrict__ w2p, const float* __restrict__ b2p,
    const float* __restrict__ g2p, const float* __restrict__ be2p,
    const float* __restrict__ m2p, const float* __restrict__ v2p,
    const float* __restrict__ t1p, const float* __restrict__ tb1p,
    const float* __restrict__ g3p, const float* __restrict__ be3p,
    const float* __restrict__ m3p, const float* __restrict__ v3p,
    const float* __restrict__ t2p, const float* __restrict__ tb2p,
    uint16_t* __restrict__ X)
{
  __shared__ __align__(16) uint16_t yTA[NROW * YT];
  __shared__ __align__(16) uint16_t yTB[NROW * YT];
  __shared__ __align__(16) uint16_t wAs[64 * AST];
  __shared__ float xs[6][YT];
  const int tid  = threadIdx.x;
  const int lane = tid & 63;
  const int wv   = tid >> 6;
  const int t    = blockIdx.y;
  const int l0   = blockIdx.x * 64;

  for (int i = tid; i < NROW * YT; i += 256) { yTA[i] = 0; yTB[i] = 0; }

  for (int i = tid; i < 6 * YT; i += 256) {
    int c = i % 6, il = i / 6;
    int gl = l0 - 2 + il;
    float v = 0.f;
    if (gl >= 0 && gl < 1024) v = inp[(size_t)t * 6144 + (size_t)gl * 6 + c];
    xs[c][il] = v;
  }

  for (int i = tid; i < 4096; i += 256) {
    int hh = i >> 6, cc = i & 63;
    float2 q = *(const float2*)(w2p + (size_t)i * 2);
    wAs[hh * AST + cc]      = f2bf(q.x);
    wAs[hh * AST + 64 + cc] = f2bf(q.y);
  }
  __syncthreads();

  // ---- phase 1 (VALU)
  {
    const int h = lane;
    float wr[12];
#pragma unroll
    for (int i = 0; i < 6; ++i) {
      float2 q = *(const float2*)(w1p + h * 12 + i * 2);
      wr[i * 2] = q.x; wr[i * 2 + 1] = q.y;
    }
    float sc = g1p[h] * __builtin_amdgcn_rsqf(v1p[h] + 1e-5f);
    float tc = (b1p[h] - m1p[h]) * sc + be1p[h];
#pragma unroll 1
    for (int base = wv * 4; base < 67; base += 16) {
      float a0 = 0, a1 = 0, a2 = 0, a3 = 0;
#pragma unroll
      for (int c = 0; c < 6; ++c) {
        float4 v = *(const float4*)&xs[c][base];
        float s4 = xs[c][base + 4];
        float k0 = wr[c * 2], k1 = wr[c * 2 + 1];
        a0 += v.x * k0 + v.y * k1;
        a1 += v.y * k0 + v.z * k1;
        a2 += v.z * k0 + v.w * k1;
        a3 += v.w * k0 + s4 * k1;
      }
      float r[4] = {a0, a1, a2, a3};
#pragma unroll
      for (int j = 0; j < 4; ++j) {
        int il = base + j;
        if (il < 67) {
          int gl = l0 - 2 + il;
          yTA[(il + 1) * YT + h] =
              (gl >= 0 && gl < 1023) ? f2bf(fmaxf(r[j] * sc + tc, 0.f)) : (uint16_t)0;
        }
      }
    }
  }
  __syncthreads();

  mfma_phase<2>(yTA, yTB, nullptr, wAs, g2p, be2p, m2p, v2p, b2p, lane, wv, l0);
  __syncthreads();

  for (int i = tid; i < 4096; i += 256) {
    int cc = i >> 6, hh = i & 63;
    float2 q = *(const float2*)(t1p + (size_t)i * 2);
    wAs[hh * AST + cc]      = f2bf(q.x);
    wAs[hh * AST + 64 + cc] = f2bf(q.y);
  }
  __syncthreads();

  mfma_phase<3>(yTB, yTA, nullptr, wAs, g3p, be3p, m3p, v3p, tb1p, lane, wv, l0);
  __syncthreads();

  for (int i = tid; i < 4096; i += 256) {
    int cc = i >> 6, hh = i & 63;
    float2 q = *(const float2*)(t2p + (size_t)i * 2);
    wAs[hh * AST + cc]      = f2bf(q.x);
    wAs[hh * AST + 64 + cc] = f2bf(q.y);
  }
  __syncthreads();

  mfma_phase<4>(yTA, nullptr, X + (size_t)(t + 1) * 65536, wAs,
                nullptr, nullptr, nullptr, nullptr, tb2p, lane, wv, l0);
}

// ============================== LSTM v10 ====================================
#define HSTR 72   // h LDS row stride (uint16): 4 rows x 64 cols

// load x A-fragment for steps T0..T0+3: A row lm = x[T0+(lm&3)][l0+(lm>>2)]
#define XLOAD(T0, XD) do {                                                     \
    if ((T0) < 512) {                                                          \
      const uint16_t* xp_ = Xb + (size_t)((T0) + 1 + (lm & 3)) * 65536         \
                          + (size_t)(l0 + (lm >> 2)) * 64 + lq * 8;            \
      XD[0] = *(const bf16x8*)xp_;                                             \
      XD[1] = *(const bf16x8*)(xp_ + 32);                                      \
    }                                                                          \
  } while (0)

// x-part gates for 4 steps, bias-seeded: AX[g][r] = bias_g + x_{T0+r}.Wih_g
#define AXCOMP(XD, AX) do {                                                    \
    AX[0] = MFMA16(XD[1], bfr[0][1], MFMA16(XD[0], bfr[0][0], seed0));         \
    AX[1] = MFMA16(XD[1], bfr[1][1], MFMA16(XD[0], bfr[1][0], seed1));         \
    AX[2] = MFMA16(XD[1], bfr[2][1], MFMA16(XD[0], bfr[2][0], seed2));         \
    AX[3] = MFMA16(XD[1], bfr[3][1], MFMA16(XD[0], bfr[3][0], seed3));         \
  } while (0)

// one step; S_ is a literal 0..3 (selects x-gate slot and LDS parity)
#define LSTM_STEP(T_, S_, AXC) do {                                            \
    bf16x8 hf0_ = *(const bf16x8*)&hl[(S_) & 1][(lm >> 2) * HSTR + lq * 8];    \
    bf16x8 hf1_ = *(const bf16x8*)&hl[(S_) & 1][(lm >> 2) * HSTR + 32 + lq * 8]; \
    if (wv == 0 && (T_) > 0) {                                                 \
      f32x4 pr_ = MFMA16(hf1_, owf1, MFMA16(hf0_, owf0, Z4));                  \
      if (lm == 0)                                                             \
        outp[(size_t)((T_) - 1) * 1024 + l0 + lq] = pr_[0] + obv;              \
    }                                                                          \
    f32x4 z0_ = MFMA16(hf1_, bfr[0][3], MFMA16(hf0_, bfr[0][2], AXC[0]));      \
    f32x4 z1_ = MFMA16(hf1_, bfr[1][3], MFMA16(hf0_, bfr[1][2], AXC[1]));      \
    f32x4 z2_ = MFMA16(hf1_, bfr[2][3], MFMA16(hf0_, bfr[2][2], AXC[2]));      \
    f32x4 z3_ = MFMA16(hf1_, bfr[3][3], MFMA16(hf0_, bfr[3][2], AXC[3]));      \
    float ii_ = fsig(z0_[S_]);                                                 \
    float ff_ = fsig(z1_[S_]);                                                 \
    float gg_ = ftanh(z2_[S_]);                                                \
    float oo_ = fsig(z3_[S_]);                                                 \
    creg  = ff_ * creg + ii_ * gg_;                                            \
    hprev = oo_ * ftanh(creg);                                                 \
    hl[((S_) + 1) & 1][lq * HSTR + hcol] = f2bf(hprev);                        \
    asm volatile("s_waitcnt lgkmcnt(0)" ::: "memory");                         \
    __builtin_amdgcn_s_barrier();                                              \
    asm volatile("" ::: "memory");                                             \
  } while (0)

__global__ __launch_bounds__(256) void lstm_k(
    const float* __restrict__ h0p, const float* __restrict__ c0p,
    const float* __restrict__ wihp, const float* __restrict__ whhp,
    const float* __restrict__ bihp, const float* __restrict__ bhhp,
    const float* __restrict__ owp, const float* __restrict__ obp,
    uint16_t* __restrict__ Xb, float* __restrict__ outp)
{
  __shared__ __align__(16) uint16_t hl[2][4 * HSTR];
  const int tid  = threadIdx.x;
  const int lane = tid & 63;
  const int wv   = tid >> 6;
  const int lm   = lane & 15;
  const int lq   = lane >> 4;
  const int l0   = blockIdx.x << 2;        // 4 batch rows per block
  const int hcol = (wv << 4) | lm;
  const f32x4 Z4 = {0.f, 0.f, 0.f, 0.f};

  // B weights (unchanged layout): bfr[g][0..1]=Wih chunks, [2..3]=Whh chunks
  bf16x8 bfr[4][4];
#pragma unroll
  for (int nt = 0; nt < 4; ++nt) {
    int n = nt * 64 + hcol;
#pragma unroll
    for (int kc = 0; kc < 4; ++kc) {
      int k0 = kc * 32 + lq * 8;
      const float* src = (k0 < 64) ? (wihp + (size_t)n * 64 + k0)
                                   : (whhp + (size_t)n * 64 + (k0 - 64));
      bf16x8 f;
#pragma unroll
      for (int j = 0; j < 8; ++j) f[j] = (short)f2bf(src[j]);
      bfr[nt][kc] = f;
    }
  }
  float bi0 = bihp[hcol]       + bhhp[hcol];
  float bi1 = bihp[64 + hcol]  + bhhp[64 + hcol];
  float bi2 = bihp[128 + hcol] + bhhp[128 + hcol];
  float bi3 = bihp[192 + hcol] + bhhp[192 + hcol];
  const f32x4 seed0 = {bi0, bi0, bi0, bi0};
  const f32x4 seed1 = {bi1, bi1, bi1, bi1};
  const f32x4 seed2 = {bi2, bi2, bi2, bi2};
  const f32x4 seed3 = {bi3, bi3, bi3, bi3};
  float obv = obp[0];

  // projection B-fragment: col 0 holds ow
  bf16x8 owf0 = {0, 0, 0, 0, 0, 0, 0, 0}, owf1 = {0, 0, 0, 0, 0, 0, 0, 0};
  if (lm == 0) {
#pragma unroll
    for (int j = 0; j < 8; ++j) {
      owf0[j] = (short)f2bf(owp[lq * 8 + j]);
      owf1[j] = (short)f2bf(owp[32 + lq * 8 + j]);
    }
  }

  // one cell per lane: (batch row lq, h-col hcol)
  float creg  = c0p[(size_t)(l0 + lq) * 64 + hcol];
  float hprev = 0.f;

  // stage h0 -> hl[0] (4 rows x 64 cols)
  {
    int row = tid >> 6, col = tid & 63;
    hl[0][row * HSTR + col] = f2bf(h0p[(size_t)(l0 + row) * 64 + col]);
  }

  bf16x8 xA[2], xB[2];
  f32x4 axA[4], axB[4];
  XLOAD(0, xA);
  AXCOMP(xA, axA);
  __syncthreads();

#pragma unroll 1
  for (int t0 = 0; t0 < 512; t0 += 8) {
    XLOAD(t0 + 4, xB);
    LSTM_STEP(t0 + 0, 0, axA);
    LSTM_STEP(t0 + 1, 1, axA);
    LSTM_STEP(t0 + 2, 2, axA);
    if (t0 + 4 < 512) AXCOMP(xB, axB);
    LSTM_STEP(t0 + 3, 3, axA);
    XLOAD(t0 + 8, xA);
    LSTM_STEP(t0 + 4, 0, axB);
    LSTM_STEP(t0 + 5, 1, axB);
    LSTM_STEP(t0 + 6, 2, axB);
    if (t0 + 8 < 512) AXCOMP(xA, axA);
    LSTM_STEP(t0 + 7, 3, axB);
  }

  // out[511]: h_511 is in hl[0] (step 511 = S_3 wrote parity 0)
  if (wv == 0) {
    bf16x8 hf0 = *(const bf16x8*)&hl[0][(lm >> 2) * HSTR + lq * 8];
    bf16x8 hf1 = *(const bf16x8*)&hl[0][(lm >> 2) * HSTR + 32 + lq * 8];
    f32x4 pr = MFMA16(hf1, owf1, MFMA16(hf0, owf0, Z4));
    if (lm == 0) outp[(size_t)511 * 1024 + l0 + lq] = pr[0] + obv;
  }

  // hT at out+524288, cT at out+589824 (fp32)
  outp[524288 + (size_t)(l0 + lq) * 64 + hcol] = hprev;
  outp[589824 + (size_t)(l0 + lq) * 64 + hcol] = creg;
}

// ============================== launch =====================================
extern "C" void kernel_launch(void* const* d_in, const int* in_sizes, int n_in,
                              void* d_out, int out_size, void* d_ws, size_t ws_size,
                              hipStream_t stream)
{
  (void)in_sizes; (void)n_in; (void)out_size;
  if (ws_size < (size_t)513 * 65536 * 2) return;   // ws guard

  const float* inp = (const float*)d_in[0];
  const float* h0p = (const float*)d_in[1];
  const float* c0p = (const float*)d_in[2];
  const float* w1  = (const float*)d_in[3];
  const float* b1  = (const float*)d_in[4];
  const float* g1  = (const float*)d_in[5];
  const float* be1 = (const float*)d_in[6];
  const float* m1  = (const float*)d_in[7];
  const float* v1  = (const float*)d_in[8];
  const float* w2  = (const float*)d_in[9];
  const float* b2  = (const float*)d_in[10];
  const float* g2  = (const float*)d_in[11];
  const float* be2 = (const float*)d_in[12];
  const float* m2  = (const float*)d_in[13];
  const float* v2  = (const float*)d_in[14];
  const float* tw1 = (const float*)d_in[15];
  const float* tb1 = (const float*)d_in[16];
  const float* g3  = (const float*)d_in[17];
  const float* be3 = (const float*)d_in[18];
  const float* m3  = (const float*)d_in[19];
  const float* v3  = (const float*)d_in[20];
  const float* tw2 = (const float*)d_in[21];
  const float* tb2 = (const float*)d_in[22];
  const float* wih = (const float*)d_in[23];
  const float* whh = (const float*)d_in[24];
  const float* bih = (const float*)d_in[25];
  const float* bhh = (const float*)d_in[26];
  const float* ow  = (const float*)d_in[27];
  const float* ob  = (const float*)d_in[28];

  uint16_t* Xb   = (uint16_t*)d_ws;
  float*    outp = (float*)d_out;

  conv_stack_k<<<dim3(16, 512), 256, 0, stream>>>(
      inp, w1, b1, g1, be1, m1, v1, w2, b2, g2, be2, m2, v2,
      tw1, tb1, g3, be3, m3, v3, tw2, tb2, Xb);
  lstm_k<<<256, 256, 0, stream>>>(h0p, c0p, wih, whh, bih, bhh, ow, ob, Xb, outp);
}

// Round 11
// 296.239 us; speedup vs baseline: 2.5256x; 1.0382x over previous
//
#include <hip/hip_runtime.h>
#include <hip/hip_bf16.h>
#include <stdint.h>

// ---------------------------------------------------------------------------
// CNNLSTM: conv stack (MFMA phases 2-4) -> LSTM(T=512,batch=1024,H=64) -> proj
// LSTM v11: 256 blocks x 4 batch rows, 4 waves x 16 gate-cols, 1 cell/lane.
//  - h history hh[8] in LDS replaces the parity buffer: step T writes slot T&7,
//    step T+1 reads slot T&7; h0 staged in slot 7. 1 ds_write/step.
//  - projection batched every 4 steps (A row i = h_{T-4+(i&3)}[row i>>2],
//    col-0 ow B-fragment -> one MFMA pair = 4 steps x 4 rows), rotating duty
//    wave; 8-slot history makes duty reads disjoint from current writes.
//  - z-MFMAs split into independent C=AXC / C=0 halves + scalar add (removes
//    one MFMA dep-latency from the h->h critical path).
// ws layout: 513 slots of 1024*64 bf16; conv writes x_t to slot t+1.
// ---------------------------------------------------------------------------

typedef __attribute__((ext_vector_type(8))) short bf16x8;
typedef __attribute__((ext_vector_type(4))) float f32x4;

__device__ __forceinline__ float bf2f(uint16_t u) {
  union { uint32_t i; float f; } v; v.i = ((uint32_t)u) << 16; return v.f;
}
__device__ __forceinline__ uint16_t f2bf(float f) {
  union { float f; uint32_t i; } v; v.f = f;
  return (uint16_t)((v.i + 0x7FFFu + ((v.i >> 16) & 1u)) >> 16);  // RNE
}
__device__ __forceinline__ float fexp(float x) { return __builtin_amdgcn_exp2f(x * 1.44269504088896340736f); }
__device__ __forceinline__ float frcp(float x) { return __builtin_amdgcn_rcpf(x); }
__device__ __forceinline__ float fsig(float x)  { return frcp(1.f + fexp(-x)); }
__device__ __forceinline__ float ftanh(float x) { return 1.f - 2.f * frcp(1.f + fexp(2.f * x)); }

#define MFMA16(a, b, c) __builtin_amdgcn_mfma_f32_16x16x32_bf16(a, b, c, 0, 0, 0)

// ============================ conv stack (unchanged) ========================
#define YT   72
#define NROW 84
#define AST  136

template<int PHASE>
__device__ __forceinline__ void mfma_phase(
    const uint16_t* yin, uint16_t* yout, uint16_t* Xg, const uint16_t* wAs,
    const float* p_g, const float* p_be, const float* p_m, const float* p_v,
    const float* p_b, int lane, int wv, int l0)
{
  const int m0 = wv * 16;
  const int lm = lane & 15, lq = lane >> 4;
  float scr[4], tcr[4];
#pragma unroll
  for (int r = 0; r < 4; ++r) {
    int hr = m0 + lq * 4 + r;
    if constexpr (PHASE == 4) {
      scr[r] = 1.f; tcr[r] = p_b[hr];
    } else {
      float s = p_g[hr] * __builtin_amdgcn_rsqf(p_v[hr] + 1e-5f);
      scr[r] = s; tcr[r] = (p_b[hr] - p_m[hr]) * s + p_be[hr];
    }
  }
  bf16x8 af[4];
#pragma unroll
  for (int kc = 0; kc < 4; ++kc)
    af[kc] = *(const bf16x8*)&wAs[(m0 + lm) * AST + kc * 32 + lq * 8];
  const f32x4 Z = {0.f, 0.f, 0.f, 0.f};
#pragma unroll
  for (int nt = 0; nt < 5; ++nt) {
    f32x4 acc = Z;
#pragma unroll
    for (int kc = 0; kc < 4; ++kc) {
      int half = kc >> 1;
      int rT = nt * 16 + lm + 1 + (PHASE == 2 ? half : -half);
      bf16x8 bf_ = *(const bf16x8*)&yin[rT * YT + (kc & 1) * 32 + lq * 8];
      acc = MFMA16(af[kc], bf_, acc);
    }
    int il = nt * 16 + lm;
    int gl = l0 - 2 + il;
#pragma unroll
    for (int r = 0; r < 4; ++r) {
      int h = m0 + lq * 4 + r;
      float v = fmaxf(acc[r] * scr[r] + tcr[r], 0.f);
      if constexpr (PHASE == 2) {
        if (il < 66) yout[(il + 1) * YT + h] = (gl >= 0 && gl < 1022) ? f2bf(v) : (uint16_t)0;
      } else if constexpr (PHASE == 3) {
        if (il >= 1 && il < 66) yout[(il + 1) * YT + h] = (gl >= 0 && gl < 1023) ? f2bf(v) : (uint16_t)0;
      } else {
        if (il >= 2 && il < 66) Xg[(size_t)gl * 64 + h] = f2bf(v);
      }
    }
  }
}

__global__ __launch_bounds__(256, 3) void conv_stack_k(
    const float* __restrict__ inp,
    const float* __restrict__ w1p, const float* __restrict__ b1p,
    const float* __restrict__ g1p, const float* __restrict__ be1p,
    const float* __restrict__ m1p, const float* __restrict__ v1p,
    const float* __restrict__ w2p, const float* __restrict__ b2p,
    const float* __restrict__ g2p, const float* __restrict__ be2p,
    const float* __restrict__ m2p, const float* __restrict__ v2p,
    const float* __restrict__ t1p, const float* __restrict__ tb1p,
    const float* __restrict__ g3p, const float* __restrict__ be3p,
    const float* __restrict__ m3p, const float* __restrict__ v3p,
    const float* __restrict__ t2p, const float* __restrict__ tb2p,
    uint16_t* __restrict__ X)
{
  __shared__ __align__(16) uint16_t yTA[NROW * YT];
  __shared__ __align__(16) uint16_t yTB[NROW * YT];
  __shared__ __align__(16) uint16_t wAs[64 * AST];
  __shared__ float xs[6][YT];
  const int tid  = threadIdx.x;
  const int lane = tid & 63;
  const int wv   = tid >> 6;
  const int t    = blockIdx.y;
  const int l0   = blockIdx.x * 64;

  for (int i = tid; i < NROW * YT; i += 256) { yTA[i] = 0; yTB[i] = 0; }

  for (int i = tid; i < 6 * YT; i += 256) {
    int c = i % 6, il = i / 6;
    int gl = l0 - 2 + il;
    float v = 0.f;
    if (gl >= 0 && gl < 1024) v = inp[(size_t)t * 6144 + (size_t)gl * 6 + c];
    xs[c][il] = v;
  }

  for (int i = tid; i < 4096; i += 256) {
    int hh = i >> 6, cc = i & 63;
    float2 q = *(const float2*)(w2p + (size_t)i * 2);
    wAs[hh * AST + cc]      = f2bf(q.x);
    wAs[hh * AST + 64 + cc] = f2bf(q.y);
  }
  __syncthreads();

  // ---- phase 1 (VALU)
  {
    const int h = lane;
    float wr[12];
#pragma unroll
    for (int i = 0; i < 6; ++i) {
      float2 q = *(const float2*)(w1p + h * 12 + i * 2);
      wr[i * 2] = q.x; wr[i * 2 + 1] = q.y;
    }
    float sc = g1p[h] * __builtin_amdgcn_rsqf(v1p[h] + 1e-5f);
    float tc = (b1p[h] - m1p[h]) * sc + be1p[h];
#pragma unroll 1
    for (int base = wv * 4; base < 67; base += 16) {
      float a0 = 0, a1 = 0, a2 = 0, a3 = 0;
#pragma unroll
      for (int c = 0; c < 6; ++c) {
        float4 v = *(const float4*)&xs[c][base];
        float s4 = xs[c][base + 4];
        float k0 = wr[c * 2], k1 = wr[c * 2 + 1];
        a0 += v.x * k0 + v.y * k1;
        a1 += v.y * k0 + v.z * k1;
        a2 += v.z * k0 + v.w * k1;
        a3 += v.w * k0 + s4 * k1;
      }
      float r[4] = {a0, a1, a2, a3};
#pragma unroll
      for (int j = 0; j < 4; ++j) {
        int il = base + j;
        if (il < 67) {
          int gl = l0 - 2 + il;
          yTA[(il + 1) * YT + h] =
              (gl >= 0 && gl < 1023) ? f2bf(fmaxf(r[j] * sc + tc, 0.f)) : (uint16_t)0;
        }
      }
    }
  }
  __syncthreads();

  mfma_phase<2>(yTA, yTB, nullptr, wAs, g2p, be2p, m2p, v2p, b2p, lane, wv, l0);
  __syncthreads();

  for (int i = tid; i < 4096; i += 256) {
    int cc = i >> 6, hh = i & 63;
    float2 q = *(const float2*)(t1p + (size_t)i * 2);
    wAs[hh * AST + cc]      = f2bf(q.x);
    wAs[hh * AST + 64 + cc] = f2bf(q.y);
  }
  __syncthreads();

  mfma_phase<3>(yTB, yTA, nullptr, wAs, g3p, be3p, m3p, v3p, tb1p, lane, wv, l0);
  __syncthreads();

  for (int i = tid; i < 4096; i += 256) {
    int cc = i >> 6, hh = i & 63;
    float2 q = *(const float2*)(t2p + (size_t)i * 2);
    wAs[hh * AST + cc]      = f2bf(q.x);
    wAs[hh * AST + 64 + cc] = f2bf(q.y);
  }
  __syncthreads();

  mfma_phase<4>(yTA, nullptr, X + (size_t)(t + 1) * 65536, wAs,
                nullptr, nullptr, nullptr, nullptr, tb2p, lane, wv, l0);
}

// ============================== LSTM v11 ====================================
#define HSTR 72   // hh row stride (uint16): rows 0..3 per slot

// load x A-fragment for steps T0..T0+3: A row lm = x[T0+(lm&3)][l0+(lm>>2)]
#define XLOAD(T0, XD) do {                                                     \
    if ((T0) < 512) {                                                          \
      const uint16_t* xp_ = Xb + (size_t)((T0) + 1 + (lm & 3)) * 65536         \
                          + (size_t)(l0 + (lm >> 2)) * 64 + lq * 8;            \
      XD[0] = *(const bf16x8*)xp_;                                             \
      XD[1] = *(const bf16x8*)(xp_ + 32);                                      \
    }                                                                          \
  } while (0)

// x-part gates for 4 steps, bias-seeded: AX[g][r] = bias_g + x_{T0+r}.Wih_g
#define AXCOMP(XD, AX) do {                                                    \
    AX[0] = MFMA16(XD[1], bfr[0][1], MFMA16(XD[0], bfr[0][0], seed0));         \
    AX[1] = MFMA16(XD[1], bfr[1][1], MFMA16(XD[0], bfr[1][0], seed1));         \
    AX[2] = MFMA16(XD[1], bfr[2][1], MFMA16(XD[0], bfr[2][0], seed2));         \
    AX[3] = MFMA16(XD[1], bfr[3][1], MFMA16(XD[0], bfr[3][0], seed3));         \
  } while (0)

// one step; K_ = literal 0..7 (hh slot), T_ = t0 + K_ (runtime)
#define LSTM_STEP(T_, K_, AXC) do {                                            \
    bf16x8 hf0_ = *(const bf16x8*)&hh[((K_) + 7) & 7][(lm >> 2) * HSTR + lq * 8];      \
    bf16x8 hf1_ = *(const bf16x8*)&hh[((K_) + 7) & 7][(lm >> 2) * HSTR + 32 + lq * 8]; \
    if ((((K_) & 3) == 0) && (T_) > 0 && wv == (((T_) >> 2) & 3)) {            \
      bf16x8 pa0_ = *(const bf16x8*)&hh[((K_) ^ 4) + (lm & 3)][(lm >> 2) * HSTR + lq * 8];      \
      bf16x8 pa1_ = *(const bf16x8*)&hh[((K_) ^ 4) + (lm & 3)][(lm >> 2) * HSTR + 32 + lq * 8]; \
      f32x4 pr_ = MFMA16(pa1_, owf1, MFMA16(pa0_, owf0, Z4));                  \
      if (lm == 0) {                                                           \
        outp[(size_t)((T_) - 4) * 1024 + l0 + lq] = pr_[0] + obv;              \
        outp[(size_t)((T_) - 3) * 1024 + l0 + lq] = pr_[1] + obv;              \
        outp[(size_t)((T_) - 2) * 1024 + l0 + lq] = pr_[2] + obv;              \
        outp[(size_t)((T_) - 1) * 1024 + l0 + lq] = pr_[3] + obv;              \
      }                                                                        \
    }                                                                          \
    f32x4 za0_ = MFMA16(hf0_, bfr[0][2], AXC[0]);                              \
    f32x4 zb0_ = MFMA16(hf1_, bfr[0][3], Z4);                                  \
    f32x4 za1_ = MFMA16(hf0_, bfr[1][2], AXC[1]);                              \
    f32x4 zb1_ = MFMA16(hf1_, bfr[1][3], Z4);                                  \
    f32x4 za2_ = MFMA16(hf0_, bfr[2][2], AXC[2]);                              \
    f32x4 zb2_ = MFMA16(hf1_, bfr[2][3], Z4);                                  \
    f32x4 za3_ = MFMA16(hf0_, bfr[3][2], AXC[3]);                              \
    f32x4 zb3_ = MFMA16(hf1_, bfr[3][3], Z4);                                  \
    float ii_ = fsig(za0_[(K_) & 3] + zb0_[(K_) & 3]);                         \
    float ff_ = fsig(za1_[(K_) & 3] + zb1_[(K_) & 3]);                         \
    float gg_ = ftanh(za2_[(K_) & 3] + zb2_[(K_) & 3]);                        \
    float oo_ = fsig(za3_[(K_) & 3] + zb3_[(K_) & 3]);                         \
    creg  = ff_ * creg + ii_ * gg_;                                            \
    hprev = oo_ * ftanh(creg);                                                 \
    hh[(K_)][lq * HSTR + hcol] = f2bf(hprev);                                  \
    asm volatile("s_waitcnt lgkmcnt(0)" ::: "memory");                         \
    __builtin_amdgcn_s_barrier();                                              \
    asm volatile("" ::: "memory");                                             \
  } while (0)

__global__ __launch_bounds__(256) void lstm_k(
    const float* __restrict__ h0p, const float* __restrict__ c0p,
    const float* __restrict__ wihp, const float* __restrict__ whhp,
    const float* __restrict__ bihp, const float* __restrict__ bhhp,
    const float* __restrict__ owp, const float* __restrict__ obp,
    uint16_t* __restrict__ Xb, float* __restrict__ outp)
{
  __shared__ __align__(16) uint16_t hh[8][4 * HSTR];   // 8-deep h history
  const int tid  = threadIdx.x;
  const int lane = tid & 63;
  const int wv   = tid >> 6;
  const int lm   = lane & 15;
  const int lq   = lane >> 4;
  const int l0   = blockIdx.x << 2;        // 4 batch rows per block
  const int hcol = (wv << 4) | lm;
  const f32x4 Z4 = {0.f, 0.f, 0.f, 0.f};

  // B weights: bfr[g][0..1]=Wih chunks, [2..3]=Whh chunks
  bf16x8 bfr[4][4];
#pragma unroll
  for (int nt = 0; nt < 4; ++nt) {
    int n = nt * 64 + hcol;
#pragma unroll
    for (int kc = 0; kc < 4; ++kc) {
      int k0 = kc * 32 + lq * 8;
      const float* src = (k0 < 64) ? (wihp + (size_t)n * 64 + k0)
                                   : (whhp + (size_t)n * 64 + (k0 - 64));
      bf16x8 f;
#pragma unroll
      for (int j = 0; j < 8; ++j) f[j] = (short)f2bf(src[j]);
      bfr[nt][kc] = f;
    }
  }
  float bi0 = bihp[hcol]       + bhhp[hcol];
  float bi1 = bihp[64 + hcol]  + bhhp[64 + hcol];
  float bi2 = bihp[128 + hcol] + bhhp[128 + hcol];
  float bi3 = bihp[192 + hcol] + bhhp[192 + hcol];
  const f32x4 seed0 = {bi0, bi0, bi0, bi0};
  const f32x4 seed1 = {bi1, bi1, bi1, bi1};
  const f32x4 seed2 = {bi2, bi2, bi2, bi2};
  const f32x4 seed3 = {bi3, bi3, bi3, bi3};
  float obv = obp[0];

  // projection B-fragment: col 0 holds ow
  bf16x8 owf0 = {0, 0, 0, 0, 0, 0, 0, 0}, owf1 = {0, 0, 0, 0, 0, 0, 0, 0};
  if (lm == 0) {
#pragma unroll
    for (int j = 0; j < 8; ++j) {
      owf0[j] = (short)f2bf(owp[lq * 8 + j]);
      owf1[j] = (short)f2bf(owp[32 + lq * 8 + j]);
    }
  }

  // one cell per lane: (batch row lq, h-col hcol)
  float creg  = c0p[(size_t)(l0 + lq) * 64 + hcol];
  float hprev = 0.f;

  // stage h0 -> hh[7] ("step -1")
  {
    int row = tid >> 6, col = tid & 63;
    hh[7][row * HSTR + col] = f2bf(h0p[(size_t)(l0 + row) * 64 + col]);
  }

  bf16x8 xA[2], xB[2];
  f32x4 axA[4], axB[4];
  XLOAD(0, xA);
  AXCOMP(xA, axA);
  __syncthreads();

#pragma unroll 1
  for (int t0 = 0; t0 < 512; t0 += 8) {
    XLOAD(t0 + 4, xB);
    LSTM_STEP(t0 + 0, 0, axA);
    LSTM_STEP(t0 + 1, 1, axA);
    LSTM_STEP(t0 + 2, 2, axA);
    if (t0 + 4 < 512) AXCOMP(xB, axB);
    LSTM_STEP(t0 + 3, 3, axA);
    XLOAD(t0 + 8, xA);
    LSTM_STEP(t0 + 4, 4, axB);
    LSTM_STEP(t0 + 5, 5, axB);
    LSTM_STEP(t0 + 6, 6, axB);
    if (t0 + 8 < 512) AXCOMP(xA, axA);
    LSTM_STEP(t0 + 7, 7, axB);
  }

  // post-loop duty: project steps 508-511 from hh slots 4-7 (wave 0)
  if (wv == 0) {
    bf16x8 pa0 = *(const bf16x8*)&hh[4 + (lm & 3)][(lm >> 2) * HSTR + lq * 8];
    bf16x8 pa1 = *(const bf16x8*)&hh[4 + (lm & 3)][(lm >> 2) * HSTR + 32 + lq * 8];
    f32x4 pr = MFMA16(pa1, owf1, MFMA16(pa0, owf0, Z4));
    if (lm == 0) {
      outp[(size_t)508 * 1024 + l0 + lq] = pr[0] + obv;
      outp[(size_t)509 * 1024 + l0 + lq] = pr[1] + obv;
      outp[(size_t)510 * 1024 + l0 + lq] = pr[2] + obv;
      outp[(size_t)511 * 1024 + l0 + lq] = pr[3] + obv;
    }
  }

  // hT at out+524288, cT at out+589824 (fp32)
  outp[524288 + (size_t)(l0 + lq) * 64 + hcol] = hprev;
  outp[589824 + (size_t)(l0 + lq) * 64 + hcol] = creg;
}

// ============================== launch =====================================
extern "C" void kernel_launch(void* const* d_in, const int* in_sizes, int n_in,
                              void* d_out, int out_size, void* d_ws, size_t ws_size,
                              hipStream_t stream)
{
  (void)in_sizes; (void)n_in; (void)out_size;
  if (ws_size < (size_t)513 * 65536 * 2) return;   // ws guard

  const float* inp = (const float*)d_in[0];
  const float* h0p = (const float*)d_in[1];
  const float* c0p = (const float*)d_in[2];
  const float* w1  = (const float*)d_in[3];
  const float* b1  = (const float*)d_in[4];
  const float* g1  = (const float*)d_in[5];
  const float* be1 = (const float*)d_in[6];
  const float* m1  = (const float*)d_in[7];
  const float* v1  = (const float*)d_in[8];
  const float* w2  = (const float*)d_in[9];
  const float* b2  = (const float*)d_in[10];
  const float* g2  = (const float*)d_in[11];
  const float* be2 = (const float*)d_in[12];
  const float* m2  = (const float*)d_in[13];
  const float* v2  = (const float*)d_in[14];
  const float* tw1 = (const float*)d_in[15];
  const float* tb1 = (const float*)d_in[16];
  const float* g3  = (const float*)d_in[17];
  const float* be3 = (const float*)d_in[18];
  const float* m3  = (const float*)d_in[19];
  const float* v3  = (const float*)d_in[20];
  const float* tw2 = (const float*)d_in[21];
  const float* tb2 = (const float*)d_in[22];
  const float* wih = (const float*)d_in[23];
  const float* whh = (const float*)d_in[24];
  const float* bih = (const float*)d_in[25];
  const float* bhh = (const float*)d_in[26];
  const float* ow  = (const float*)d_in[27];
  const float* ob  = (const float*)d_in[28];

  uint16_t* Xb   = (uint16_t*)d_ws;
  float*    outp = (float*)d_out;

  conv_stack_k<<<dim3(16, 512), 256, 0, stream>>>(
      inp, w1, b1, g1, be1, m1, v1, w2, b2, g2, be2, m2, v2,
      tw1, tb1, g3, be3, m3, v3, tw2, tb2, Xb);
  lstm_k<<<256, 256, 0, stream>>>(h0p, c0p, wih, whh, bih, bhh, ow, ob, Xb, outp);
}

// Round 12
// 225.801 us; speedup vs baseline: 3.3135x; 1.3119x over previous
//
#include <hip/hip_runtime.h>
#include <hip/hip_bf16.h>
#include <stdint.h>

// ---------------------------------------------------------------------------
// CNNLSTM: conv stack (MFMA phases 2-4) -> LSTM(T=512,batch=1024,H=64) -> proj
// v12:
//  prep_k (one-time): conv weights W2/T1/T2 -> bf16 A-fragment layout in ws
//    slot 0 (unused); BN scale/shift precomputed. conv loads A-fragments from
//    global (L2-hot) -> wAs LDS + 3 staging loops + zero-init deleted.
//  LSTM: AXCOMP dribbled 2 MFMAs/step after the h-write (off the chain);
//    log2e folded into gate weights/biases (exp2 direct); h cvt via native
//    v_cvt_pk_bf16_f32; running x pointers.
// ws layout: slot 0 = weights (W2a[8192] T1a[8192] T2a[8192] bf16, F[512] f32);
//   slots 1..512 = x_t (conv out, bf16). ws bytes: 513*65536*2.
// ---------------------------------------------------------------------------

typedef __attribute__((ext_vector_type(8))) short bf16x8;
typedef __attribute__((ext_vector_type(4))) float f32x4;

__device__ __forceinline__ uint16_t f2bf(float f) {
  union { float f; uint32_t i; } v; v.f = f;
  return (uint16_t)((v.i + 0x7FFFu + ((v.i >> 16) & 1u)) >> 16);  // RNE
}
__device__ __forceinline__ float frcp(float x) { return __builtin_amdgcn_rcpf(x); }
// pre-scaled variants: z already multiplied by log2e (sig) / 2*log2e (tanh)
__device__ __forceinline__ float fsig2(float z)  { return frcp(1.f + __builtin_amdgcn_exp2f(-z)); }
__device__ __forceinline__ float ftanh2(float z) { return 1.f - 2.f * frcp(1.f + __builtin_amdgcn_exp2f(z)); }

#define MFMA16(a, b, c) __builtin_amdgcn_mfma_f32_16x16x32_bf16(a, b, c, 0, 0, 0)

// ============================ prep kernel ===================================
// W2a[h*128+k]: k<64 -> w2[h][c=k][0], k>=64 -> w2[h][c=k-64][1]   (w2p: [h][c][k])
// T1a[h*128+k]: t1p[(k&63)*128 + h*2 + (k>>6)]                     (t1p: [c][h][k])
// T2a: same from t2p. F[512]: sc1,tc1,sc2,tc2,sc3,tc3,ones,tb2 (64 each).
__global__ __launch_bounds__(256) void prep_k(
    const float* __restrict__ w2p, const float* __restrict__ t1p,
    const float* __restrict__ t2p,
    const float* __restrict__ g1, const float* __restrict__ be1,
    const float* __restrict__ m1, const float* __restrict__ v1,
    const float* __restrict__ b1,
    const float* __restrict__ g2, const float* __restrict__ be2,
    const float* __restrict__ m2, const float* __restrict__ v2,
    const float* __restrict__ b2,
    const float* __restrict__ g3, const float* __restrict__ be3,
    const float* __restrict__ m3, const float* __restrict__ v3,
    const float* __restrict__ tb1, const float* __restrict__ tb2,
    uint16_t* __restrict__ W)
{
  int idx = blockIdx.x * 256 + threadIdx.x;
  if (idx < 8192) {
    int h = idx >> 7, k = idx & 127;
    W[idx] = f2bf(w2p[h * 128 + (k & 63) * 2 + (k >> 6)]);
  } else if (idx < 16384) {
    int i = idx - 8192; int h = i >> 7, k = i & 127;
    W[idx] = f2bf(t1p[(k & 63) * 128 + h * 2 + (k >> 6)]);
  } else if (idx < 24576) {
    int i = idx - 16384; int h = i >> 7, k = i & 127;
    W[idx] = f2bf(t2p[(k & 63) * 128 + h * 2 + (k >> 6)]);
  } else if (idx < 25088) {
    int i = idx - 24576;            // 0..511
    float* F = (float*)(W + 24576);
    int h = i & 63, sel = i >> 6;
    float val;
    if (sel == 0)      val = g1[h] * __builtin_amdgcn_rsqf(v1[h] + 1e-5f);
    else if (sel == 1) { float s = g1[h] * __builtin_amdgcn_rsqf(v1[h] + 1e-5f);
                         val = (b1[h] - m1[h]) * s + be1[h]; }
    else if (sel == 2) val = g2[h] * __builtin_amdgcn_rsqf(v2[h] + 1e-5f);
    else if (sel == 3) { float s = g2[h] * __builtin_amdgcn_rsqf(v2[h] + 1e-5f);
                         val = (b2[h] - m2[h]) * s + be2[h]; }
    else if (sel == 4) val = g3[h] * __builtin_amdgcn_rsqf(v3[h] + 1e-5f);
    else if (sel == 5) { float s = g3[h] * __builtin_amdgcn_rsqf(v3[h] + 1e-5f);
                         val = (tb1[h] - m3[h]) * s + be3[h]; }
    else if (sel == 6) val = 1.0f;
    else               val = tb2[h];
    F[i] = val;
  }
}

// ============================ conv stack ===================================
#define YT   72
#define NROW 84

// PHASE 2: taps (il, il+1); PHASE 3/4: taps (il, il-1). Output rows of yT are
// il+1; garbage rows (0, 68..83) feed only store-masked outputs -> no zeroing.
template<int PHASE>
__device__ __forceinline__ void mfma_phase(
    const uint16_t* yin, uint16_t* yout, uint16_t* Xg,
    const uint16_t* __restrict__ wAg,          // global A-layout [64][128]
    const float* __restrict__ p_sc, const float* __restrict__ p_tc,
    int lane, int wv, int l0)
{
  const int m0 = wv * 16;
  const int lm = lane & 15, lq = lane >> 4;
  bf16x8 af[4];
#pragma unroll
  for (int kc = 0; kc < 4; ++kc)
    af[kc] = *(const bf16x8*)&wAg[(m0 + lm) * 128 + kc * 32 + lq * 8];
  float scr[4], tcr[4];
#pragma unroll
  for (int r = 0; r < 4; ++r) {
    int hr = m0 + lq * 4 + r;
    scr[r] = p_sc[hr]; tcr[r] = p_tc[hr];
  }
  const f32x4 Z = {0.f, 0.f, 0.f, 0.f};
#pragma unroll
  for (int nt = 0; nt < 5; ++nt) {
    f32x4 acc = Z;
#pragma unroll
    for (int kc = 0; kc < 4; ++kc) {
      int half = kc >> 1;
      int rT = nt * 16 + lm + 1 + (PHASE == 2 ? half : -half);
      bf16x8 bf_ = *(const bf16x8*)&yin[rT * YT + (kc & 1) * 32 + lq * 8];
      acc = MFMA16(af[kc], bf_, acc);
    }
    int il = nt * 16 + lm;
    int gl = l0 - 2 + il;
#pragma unroll
    for (int r = 0; r < 4; ++r) {
      int h = m0 + lq * 4 + r;
      float v = fmaxf(acc[r] * scr[r] + tcr[r], 0.f);
      if constexpr (PHASE == 2) {
        if (il < 66) yout[(il + 1) * YT + h] = (gl >= 0 && gl < 1022) ? f2bf(v) : (uint16_t)0;
      } else if constexpr (PHASE == 3) {
        if (il >= 1 && il < 66) yout[(il + 1) * YT + h] = (gl >= 0 && gl < 1023) ? f2bf(v) : (uint16_t)0;
      } else {
        if (il >= 2 && il < 66) Xg[(size_t)gl * 64 + h] = f2bf(v);
      }
    }
  }
}

__global__ __launch_bounds__(256, 6) void conv_stack_k(
    const float* __restrict__ inp, const float* __restrict__ w1p,
    const float* __restrict__ F,
    const uint16_t* __restrict__ W2a, const uint16_t* __restrict__ T1a,
    const uint16_t* __restrict__ T2a,
    uint16_t* __restrict__ X)
{
  __shared__ __align__(16) uint16_t yTA[NROW * YT];
  __shared__ __align__(16) uint16_t yTB[NROW * YT];
  __shared__ float xs[6][YT];
  const int tid  = threadIdx.x;
  const int lane = tid & 63;
  const int wv   = tid >> 6;
  const int t    = blockIdx.y;
  const int l0   = blockIdx.x * 64;

  // stage input window xs[c][il], gl = l0-2+il (zero outside [0,1024))
  for (int i = tid; i < 6 * YT; i += 256) {
    int c = i % 6, il = i / 6;
    int gl = l0 - 2 + il;
    float v = 0.f;
    if (gl >= 0 && gl < 1024) v = inp[(size_t)t * 6144 + (size_t)gl * 6 + c];
    xs[c][il] = v;
  }

  // ---- phase 1 (VALU): y1 = relu(bn1(conv1(x))), write yTA rows 1..67
  {
    const int h = lane;
    float wr[12];
#pragma unroll
    for (int i = 0; i < 6; ++i) {
      float2 q = *(const float2*)(w1p + h * 12 + i * 2);
      wr[i * 2] = q.x; wr[i * 2 + 1] = q.y;
    }
    float sc = F[h], tc = F[64 + h];
    __syncthreads();   // xs ready
#pragma unroll 1
    for (int base = wv * 4; base < 67; base += 16) {
      float a0 = 0, a1 = 0, a2 = 0, a3 = 0;
#pragma unroll
      for (int c = 0; c < 6; ++c) {
        float4 v = *(const float4*)&xs[c][base];
        float s4 = xs[c][base + 4];
        float k0 = wr[c * 2], k1 = wr[c * 2 + 1];
        a0 += v.x * k0 + v.y * k1;
        a1 += v.y * k0 + v.z * k1;
        a2 += v.z * k0 + v.w * k1;
        a3 += v.w * k0 + s4 * k1;
      }
      float r[4] = {a0, a1, a2, a3};
#pragma unroll
      for (int j = 0; j < 4; ++j) {
        int il = base + j;
        if (il < 67) {
          int gl = l0 - 2 + il;
          yTA[(il + 1) * YT + h] =
              (gl >= 0 && gl < 1023) ? f2bf(fmaxf(r[j] * sc + tc, 0.f)) : (uint16_t)0;
        }
      }
    }
  }
  __syncthreads();

  mfma_phase<2>(yTA, yTB, nullptr, W2a, F + 128, F + 192, lane, wv, l0);
  __syncthreads();
  mfma_phase<3>(yTB, yTA, nullptr, T1a, F + 256, F + 320, lane, wv, l0);
  __syncthreads();
  mfma_phase<4>(yTA, nullptr, X + (size_t)(t + 1) * 65536, T2a,
                F + 384, F + 448, lane, wv, l0);
}

// ============================== LSTM v12 ====================================
// 256 blocks x 4 batch rows, 4 waves x 16 gate-cols, 1 cell/lane.
// Gate weights/biases pre-scaled by log2e (i,f,o) / 2*log2e (g) -> exp2 direct.
// AXCOMP dribbled: one gate's chained MFMA pair per step, after the h-write.
#define HSTR 72

// one step; K_ literal 0..7 (hh slot & step-in-batch), DG literal dribble gate
#define LSTM_STEP(T_, K_, AXC, DG, XD, AXN) do {                               \
    bf16x8 hf0_ = *(const bf16x8*)&hh[((K_) + 7) & 7][(lm >> 2) * HSTR + lq * 8];      \
    bf16x8 hf1_ = *(const bf16x8*)&hh[((K_) + 7) & 7][(lm >> 2) * HSTR + 32 + lq * 8]; \
    if ((((K_) & 3) == 0) && (T_) > 0 && wv == (((T_) >> 2) & 3)) {            \
      bf16x8 pa0_ = *(const bf16x8*)&hh[((K_) ^ 4) + (lm & 3)][(lm >> 2) * HSTR + lq * 8];      \
      bf16x8 pa1_ = *(const bf16x8*)&hh[((K_) ^ 4) + (lm & 3)][(lm >> 2) * HSTR + 32 + lq * 8]; \
      f32x4 pr_ = MFMA16(pa1_, owf1, MFMA16(pa0_, owf0, Z4));                  \
      if (lm == 0) {                                                           \
        outp[(size_t)((T_) - 4) * 1024 + l0 + lq] = pr_[0] + obv;              \
        outp[(size_t)((T_) - 3) * 1024 + l0 + lq] = pr_[1] + obv;              \
        outp[(size_t)((T_) - 2) * 1024 + l0 + lq] = pr_[2] + obv;              \
        outp[(size_t)((T_) - 1) * 1024 + l0 + lq] = pr_[3] + obv;              \
      }                                                                        \
    }                                                                          \
    f32x4 za0_ = MFMA16(hf0_, bfr[0][2], AXC[0]);                              \
    f32x4 zb0_ = MFMA16(hf1_, bfr[0][3], Z4);                                  \
    f32x4 za1_ = MFMA16(hf0_, bfr[1][2], AXC[1]);                              \
    f32x4 zb1_ = MFMA16(hf1_, bfr[1][3], Z4);                                  \
    f32x4 za2_ = MFMA16(hf0_, bfr[2][2], AXC[2]);                              \
    f32x4 zb2_ = MFMA16(hf1_, bfr[2][3], Z4);                                  \
    f32x4 za3_ = MFMA16(hf0_, bfr[3][2], AXC[3]);                              \
    f32x4 zb3_ = MFMA16(hf1_, bfr[3][3], Z4);                                  \
    float ii_ = fsig2(za0_[(K_) & 3] + zb0_[(K_) & 3]);                        \
    float ff_ = fsig2(za1_[(K_) & 3] + zb1_[(K_) & 3]);                        \
    float gg_ = ftanh2(za2_[(K_) & 3] + zb2_[(K_) & 3]);                       \
    float oo_ = fsig2(za3_[(K_) & 3] + zb3_[(K_) & 3]);                        \
    creg  = ff_ * creg + ii_ * gg_;                                            \
    float th_ = 1.f - 2.f * frcp(1.f + __builtin_amdgcn_exp2f(creg * 2.88539008177793f)); \
    hprev = oo_ * th_;                                                         \
    uint32_t hw_;                                                              \
    asm("v_cvt_pk_bf16_f32 %0, %1, %2" : "=v"(hw_) : "v"(hprev), "v"(0.f));    \
    hh[(K_)][lq * HSTR + hcol] = (uint16_t)hw_;                                \
    AXN[DG] = MFMA16(XD[1], bfr[DG][1], MFMA16(XD[0], bfr[DG][0], seeds[DG])); \
    asm volatile("s_waitcnt lgkmcnt(0)" ::: "memory");                         \
    __builtin_amdgcn_s_barrier();                                              \
    asm volatile("" ::: "memory");                                             \
  } while (0)

__global__ __launch_bounds__(256) void lstm_k(
    const float* __restrict__ h0p, const float* __restrict__ c0p,
    const float* __restrict__ wihp, const float* __restrict__ whhp,
    const float* __restrict__ bihp, const float* __restrict__ bhhp,
    const float* __restrict__ owp, const float* __restrict__ obp,
    uint16_t* __restrict__ Xb, float* __restrict__ outp)
{
  __shared__ __align__(16) uint16_t hh[8][4 * HSTR];   // 8-deep h history
  const int tid  = threadIdx.x;
  const int lane = tid & 63;
  const int wv   = tid >> 6;
  const int lm   = lane & 15;
  const int lq   = lane >> 4;
  const int l0   = blockIdx.x << 2;        // 4 batch rows per block
  const int hcol = (wv << 4) | lm;
  const f32x4 Z4 = {0.f, 0.f, 0.f, 0.f};
  const float L2E = 1.44269504088896340736f;

  // B weights, pre-scaled: i,f,o x log2e ; g x 2*log2e
  bf16x8 bfr[4][4];
#pragma unroll
  for (int nt = 0; nt < 4; ++nt) {
    float sg = (nt == 2) ? 2.f * L2E : L2E;
    int n = nt * 64 + hcol;
#pragma unroll
    for (int kc = 0; kc < 4; ++kc) {
      int k0 = kc * 32 + lq * 8;
      const float* src = (k0 < 64) ? (wihp + (size_t)n * 64 + k0)
                                   : (whhp + (size_t)n * 64 + (k0 - 64));
      bf16x8 f;
#pragma unroll
      for (int j = 0; j < 8; ++j) f[j] = (short)f2bf(src[j] * sg);
      bfr[nt][kc] = f;
    }
  }
  float bi0 = (bihp[hcol]       + bhhp[hcol])       * L2E;
  float bi1 = (bihp[64 + hcol]  + bhhp[64 + hcol])  * L2E;
  float bi2 = (bihp[128 + hcol] + bhhp[128 + hcol]) * 2.f * L2E;
  float bi3 = (bihp[192 + hcol] + bhhp[192 + hcol]) * L2E;
  f32x4 seeds[4];
  seeds[0] = f32x4{bi0, bi0, bi0, bi0};
  seeds[1] = f32x4{bi1, bi1, bi1, bi1};
  seeds[2] = f32x4{bi2, bi2, bi2, bi2};
  seeds[3] = f32x4{bi3, bi3, bi3, bi3};
  float obv = obp[0];

  // projection B-fragment: col 0 holds ow (true units)
  bf16x8 owf0 = {0, 0, 0, 0, 0, 0, 0, 0}, owf1 = {0, 0, 0, 0, 0, 0, 0, 0};
  if (lm == 0) {
#pragma unroll
    for (int j = 0; j < 8; ++j) {
      owf0[j] = (short)f2bf(owp[lq * 8 + j]);
      owf1[j] = (short)f2bf(owp[32 + lq * 8 + j]);
    }
  }

  // one cell per lane: (batch row lq, h-col hcol)
  float creg  = c0p[(size_t)(l0 + lq) * 64 + hcol];
  float hprev = 0.f;

  // stage h0 -> hh[7] ("step -1")
  {
    int row = tid >> 6, col = tid & 63;
    hh[7][row * HSTR + col] = f2bf(h0p[(size_t)(l0 + row) * 64 + col]);
  }

  // running x pointers: batch t0 reads slots t0+1..t0+4
  const uint16_t* pA = Xb + (size_t)(1 + (lm & 3)) * 65536
                     + (size_t)(l0 + (lm >> 2)) * 64 + lq * 8;
  const uint16_t* pB = pA + (size_t)4 * 65536;
  bf16x8 xA[2], xB[2];
  xA[0] = *(const bf16x8*)pA; xA[1] = *(const bf16x8*)(pA + 32);
  pA += (size_t)8 * 65536;
  xB[0] = *(const bf16x8*)pB; xB[1] = *(const bf16x8*)(pB + 32);
  pB += (size_t)8 * 65536;

  f32x4 axA[4], axB[4];
#pragma unroll
  for (int g = 0; g < 4; ++g)
    axA[g] = MFMA16(xA[1], bfr[g][1], MFMA16(xA[0], bfr[g][0], seeds[g]));
  __syncthreads();

#pragma unroll 1
  for (int t0 = 0; t0 < 512; t0 += 8) {
    if (t0 + 8 < 512) {          // xA <- batch t0+8 (dribbled at steps 4-7)
      xA[0] = *(const bf16x8*)pA; xA[1] = *(const bf16x8*)(pA + 32);
      pA += (size_t)8 * 65536;
    }
    LSTM_STEP(t0 + 0, 0, axA, 0, xB, axB);
    LSTM_STEP(t0 + 1, 1, axA, 1, xB, axB);
    LSTM_STEP(t0 + 2, 2, axA, 2, xB, axB);
    LSTM_STEP(t0 + 3, 3, axA, 3, xB, axB);
    if (t0 + 12 < 512) {         // xB <- batch t0+12 (dribbled next iter 0-3)
      xB[0] = *(const bf16x8*)pB; xB[1] = *(const bf16x8*)(pB + 32);
      pB += (size_t)8 * 65536;
    }
    LSTM_STEP(t0 + 4, 4, axB, 0, xA, axA);
    LSTM_STEP(t0 + 5, 5, axB, 1, xA, axA);
    LSTM_STEP(t0 + 6, 6, axB, 2, xA, axA);
    LSTM_STEP(t0 + 7, 7, axB, 3, xA, axA);
  }

  // post-loop duty: project steps 508-511 from hh slots 4-7 (wave 0)
  if (wv == 0) {
    bf16x8 pa0 = *(const bf16x8*)&hh[4 + (lm & 3)][(lm >> 2) * HSTR + lq * 8];
    bf16x8 pa1 = *(const bf16x8*)&hh[4 + (lm & 3)][(lm >> 2) * HSTR + 32 + lq * 8];
    f32x4 pr = MFMA16(pa1, owf1, MFMA16(pa0, owf0, Z4));
    if (lm == 0) {
      outp[(size_t)508 * 1024 + l0 + lq] = pr[0] + obv;
      outp[(size_t)509 * 1024 + l0 + lq] = pr[1] + obv;
      outp[(size_t)510 * 1024 + l0 + lq] = pr[2] + obv;
      outp[(size_t)511 * 1024 + l0 + lq] = pr[3] + obv;
    }
  }

  // hT at out+524288, cT at out+589824 (fp32)
  outp[524288 + (size_t)(l0 + lq) * 64 + hcol] = hprev;
  outp[589824 + (size_t)(l0 + lq) * 64 + hcol] = creg;
}

// ============================== launch =====================================
extern "C" void kernel_launch(void* const* d_in, const int* in_sizes, int n_in,
                              void* d_out, int out_size, void* d_ws, size_t ws_size,
                              hipStream_t stream)
{
  (void)in_sizes; (void)n_in; (void)out_size;
  if (ws_size < (size_t)513 * 65536 * 2) return;   // ws guard

  const float* inp = (const float*)d_in[0];
  const float* h0p = (const float*)d_in[1];
  const float* c0p = (const float*)d_in[2];
  const float* w1  = (const float*)d_in[3];
  const float* b1  = (const float*)d_in[4];
  const float* g1  = (const float*)d_in[5];
  const float* be1 = (const float*)d_in[6];
  const float* m1  = (const float*)d_in[7];
  const float* v1  = (const float*)d_in[8];
  const float* w2  = (const float*)d_in[9];
  const float* b2  = (const float*)d_in[10];
  const float* g2  = (const float*)d_in[11];
  const float* be2 = (const float*)d_in[12];
  const float* m2  = (const float*)d_in[13];
  const float* v2  = (const float*)d_in[14];
  const float* tw1 = (const float*)d_in[15];
  const float* tb1 = (const float*)d_in[16];
  const float* g3  = (const float*)d_in[17];
  const float* be3 = (const float*)d_in[18];
  const float* m3  = (const float*)d_in[19];
  const float* v3  = (const float*)d_in[20];
  const float* tw2 = (const float*)d_in[21];
  const float* tb2 = (const float*)d_in[22];
  const float* wih = (const float*)d_in[23];
  const float* whh = (const float*)d_in[24];
  const float* bih = (const float*)d_in[25];
  const float* bhh = (const float*)d_in[26];
  const float* ow  = (const float*)d_in[27];
  const float* ob  = (const float*)d_in[28];

  uint16_t* Xb   = (uint16_t*)d_ws;
  float*    outp = (float*)d_out;

  // slot 0 of Xb: W2a[0,8192) T1a[8192,16384) T2a[16384,24576) F(f32 x512)
  const uint16_t* W2a = Xb;
  const uint16_t* T1a = Xb + 8192;
  const uint16_t* T2a = Xb + 16384;
  const float*    F   = (const float*)(Xb + 24576);

  prep_k<<<98, 256, 0, stream>>>(w2, tw1, tw2,
                                 g1, be1, m1, v1, b1,
                                 g2, be2, m2, v2, b2,
                                 g3, be3, m3, v3, tb1, tb2, Xb);
  conv_stack_k<<<dim3(16, 512), 256, 0, stream>>>(inp, w1, F, W2a, T1a, T2a, Xb);
  lstm_k<<<256, 256, 0, stream>>>(h0p, c0p, wih, whh, bih, bhh, ow, ob, Xb, outp);
}